// Round 8
// baseline (4321.714 us; speedup 1.0000x reference)
//
#include <hip/hip_runtime.h>
#include <hip/hip_bf16.h>
#include <math.h>

#define CMDN   2
#define LIDARN 360
#define HN     256
#define TN     50
#define BATCH  2048
#define KXN    362              // CMD+LIDAR
#define NG     1024             // 4*H gate columns
#define KP     384              // padded x-K for big GEMMs
#define MR     (TN*BATCH)       // 102400 rows (t-major: r = t*2048 + b)
#define SLAB   ((size_t)BATCH*HN)

typedef __attribute__((ext_vector_type(8))) short bf16x8;
typedef __attribute__((ext_vector_type(4))) float f32x4;

__device__ inline unsigned short f2b(float f) {
    unsigned int x = __builtin_bit_cast(unsigned int, f);
    x += 0x7FFFu + ((x >> 16) & 1u);
    return (unsigned short)(x >> 16);
}
__device__ inline float b2f(unsigned short u) {
    unsigned int x = ((unsigned int)u) << 16;
    return __builtin_bit_cast(float, x);
}
__device__ inline float sigf(float x)  { return 1.f / (1.f + __expf(-x)); }
__device__ inline float tanhfa(float x){ return 2.f / (1.f + __expf(-2.f * x)) - 1.f; }

// packed gate-col order: p = 4*u + g  ->  original row jorig = g*256 + u
__device__ inline int p2j(int p) { return ((p & 3) << 8) + (p >> 2); }

// ---------------------------------------------------------------------------
// 128x128 MFMA GEMM with chunked XCD swizzle (proven rounds 4-7).
// AMODE 0: A bf16 [M][K].  AMODE 1: A = past fp32 with (b,t) remap + zero-pad.
// OMODE 0: C f32 = acc+bias. OMODE 1: outproj remap to out[b][t][col], col<360.
// OMODE 2: C bf16 = acc+bias.
// ---------------------------------------------------------------------------
template<int OMODE, int AMODE>
__global__ __launch_bounds__(256) void gemm128(
    const unsigned short* __restrict__ A,
    const float* __restrict__ Af,
    const unsigned short* __restrict__ B,
    const float* __restrict__ bias,
    void* __restrict__ Cv,
    int K, int ldc)
{
    __shared__ __align__(16) unsigned short As[128][40];
    __shared__ __align__(16) unsigned short Bs[128][40];

    const int nwg = gridDim.x * gridDim.y;
    const int hid = blockIdx.y * gridDim.x + blockIdx.x;
    const int lid = (hid & 7) * (nwg >> 3) + (hid >> 3);
    const int bx  = lid % gridDim.x;
    const int by  = lid / gridDim.x;

    const int tid  = threadIdx.x;
    const int lane = tid & 63;
    const int wv   = tid >> 6;
    const int wm   = wv >> 1, wn = wv & 1;
    const int r0   = by * 128;
    const int n0   = bx * 128;
    const int l15  = lane & 15;
    const int kb   = (lane >> 4) << 3;
    const int row1 = tid >> 2, q1 = tid & 3;

    f32x4 acc[4][4] = {};

    for (int k0 = 0; k0 < K; k0 += 32) {
        if (AMODE == 0) {
            *(bf16x8*)&As[row1][q1 * 8] =
                *(const bf16x8*)&A[(size_t)(r0 + row1) * K + k0 + q1 * 8];
            *(bf16x8*)&As[row1 + 64][q1 * 8] =
                *(const bf16x8*)&A[(size_t)(r0 + row1 + 64) * K + k0 + q1 * 8];
        } else {
            #pragma unroll
            for (int hh = 0; hh < 2; ++hh) {
                const int r  = r0 + row1 + hh * 64;
                const int tt = r >> 11, bb = r & 2047;
                const float* p = Af + ((size_t)bb * TN + tt) * KXN;
                const int kbase = k0 + q1 * 8;
                bf16x8 v;
                if (kbase + 8 <= KXN) {
                    float2 f0 = *(const float2*)(p + kbase);
                    float2 f1 = *(const float2*)(p + kbase + 2);
                    float2 f2 = *(const float2*)(p + kbase + 4);
                    float2 f3 = *(const float2*)(p + kbase + 6);
                    v[0] = (short)f2b(f0.x); v[1] = (short)f2b(f0.y);
                    v[2] = (short)f2b(f1.x); v[3] = (short)f2b(f1.y);
                    v[4] = (short)f2b(f2.x); v[5] = (short)f2b(f2.y);
                    v[6] = (short)f2b(f3.x); v[7] = (short)f2b(f3.y);
                } else {
                    #pragma unroll
                    for (int e = 0; e < 8; ++e) {
                        int k = kbase + e;
                        v[e] = (k < KXN) ? (short)f2b(p[k]) : (short)0;
                    }
                }
                *(bf16x8*)&As[row1 + hh * 64][q1 * 8] = v;
            }
        }
        *(bf16x8*)&Bs[row1][q1 * 8] =
            *(const bf16x8*)&B[(size_t)(n0 + row1) * K + k0 + q1 * 8];
        *(bf16x8*)&Bs[row1 + 64][q1 * 8] =
            *(const bf16x8*)&B[(size_t)(n0 + row1 + 64) * K + k0 + q1 * 8];
        __syncthreads();
        bf16x8 a[4], b[4];
        #pragma unroll
        for (int i = 0; i < 4; ++i) {
            a[i] = *(const bf16x8*)&As[wm * 64 + i * 16 + l15][kb];
            b[i] = *(const bf16x8*)&Bs[wn * 64 + i * 16 + l15][kb];
        }
        #pragma unroll
        for (int mi = 0; mi < 4; ++mi)
            #pragma unroll
            for (int ni = 0; ni < 4; ++ni)
                acc[mi][ni] = __builtin_amdgcn_mfma_f32_16x16x32_bf16(a[mi], b[ni], acc[mi][ni], 0, 0, 0);
        __syncthreads();
    }

    #pragma unroll
    for (int mi = 0; mi < 4; ++mi) {
        const int rowb = r0 + wm * 64 + mi * 16 + ((lane >> 4) << 2);
        #pragma unroll
        for (int ni = 0; ni < 4; ++ni) {
            const int col = n0 + wn * 64 + ni * 16 + l15;
            #pragma unroll
            for (int r = 0; r < 4; ++r) {
                const int row = rowb + r;
                float v = acc[mi][ni][r];
                if (OMODE == 0) {
                    ((float*)Cv)[(size_t)row * ldc + col] = v + bias[col];
                } else if (OMODE == 2) {
                    ((unsigned short*)Cv)[(size_t)row * ldc + col] = f2b(v + bias[col]);
                } else {
                    if (col < LIDARN) {
                        int t = row >> 11, b = row & 2047;
                        ((float*)Cv)[(size_t)b * (TN * LIDARN) + (size_t)t * LIDARN + col] = v + bias[col];
                    }
                }
            }
        }
    }
}

// ---------------------------------------------------------------------------
// Persistent recurrence v3: 256 blocks (32 rg x 8 cg) x 512 threads.
// blk = cg*32 + rg  ->  all 8 cg-peers of a rg land on the same XCD (blk%8).
// Block: 64 batch rows x 128 gate cols. W slice (64 KB) LDS-RESIDENT per phase.
// h exchanged through global (same-XCD L2) with per-rg flag barrier.
// c in registers. Additive slab (xw / l0w-bf16) double-buffered in LDS,
// prefetched during MFMAs of the previous step.
// ---------------------------------------------------------------------------
__global__ __launch_bounds__(512, 1) void recur_flags(
    const unsigned short* __restrict__ xw,      // [50][2048][1024] bf16 (x@Wih+eb)
    const unsigned short* __restrict__ l0wb,    // [2048][1024] bf16 (lidar0@Wl+db)
    const float* __restrict__ biasf,            // [1024] folded dec bias
    const float* __restrict__ cmdw,             // [1024][2]
    const float* __restrict__ cmds,             // [2048][50][2] f32
    const unsigned short* __restrict__ Wf_enc,  // frag-packed [64cf][8kf][64][8]
    const unsigned short* __restrict__ Wf_dec0,
    const unsigned short* __restrict__ Wf_dec,
    unsigned short* __restrict__ hpp,           // [2][2048][256] bf16 ping-pong
    unsigned short* __restrict__ hdec,          // [50][2048][256] bf16
    int* __restrict__ flags)                    // [32][8], zeroed per launch
{
    __shared__ __align__(16) unsigned short Wl[32768];     // 64 KB: [8cf][8kf][64][8]
    __shared__ __align__(16) unsigned short Hl[64 * 264];  // 33 KB (pad 256->264)
    __shared__ __align__(16) unsigned short Xl[2 * 8192];  // 32 KB: 2 x [64][128]
    __shared__ __align__(8)  float cmdl[64][2];

    const int tid  = threadIdx.x;
    const int lane = tid & 63;
    const int w    = tid >> 6;            // wave 0..7
    const int wm   = w >> 2, wn = w & 3;  // 2 row-halves x 4 col-quarters
    const int l15  = lane & 15;
    const int lhi  = lane >> 4;
    const int g    = l15 & 3;             // gate 0=i 1=f 2=g 3=o
    const int blk  = blockIdx.x;
    const int cg   = blk >> 5;            // 0..7 col-group
    const int rg   = blk & 31;            // 0..31 row-group
    const int r0   = rg * 64;
    int* const myflags = flags + rg * 8;

    // per-lane decoder constants (col p = cg*128 + wn*32 + ni*16 + l15)
    float bf_r[2], w0_r[2], w1_r[2];
    #pragma unroll
    for (int ni = 0; ni < 2; ++ni) {
        const int p = cg * 128 + wn * 32 + ni * 16 + l15;
        bf_r[ni] = biasf[p];
        w0_r[ni] = cmdw[p * 2];
        w1_r[ni] = cmdw[p * 2 + 1];
    }

    // ---- prologue staging: W(enc), Xl for s=1, Hl = 0 ----
    {
        const unsigned short* src = Wf_enc + (size_t)cg * 32768;
        #pragma unroll
        for (int i = 0; i < 8; ++i) {
            const int c = i * 512 + tid;
            *(bf16x8*)&Wl[c * 8] = *(const bf16x8*)&src[c * 8];
        }
        const unsigned short* xs = xw + (size_t)r0 * NG + cg * 128;
        #pragma unroll
        for (int i = 0; i < 2; ++i) {
            const int c = i * 512 + tid;                  // 0..1023
            *(bf16x8*)&Xl[8192 + (c >> 4) * 128 + (c & 15) * 8] =
                *(const bf16x8*)&xs[(size_t)(c >> 4) * NG + (c & 15) * 8];
        }
        const bf16x8 z = {0, 0, 0, 0, 0, 0, 0, 0};
        for (int i = tid; i < 64 * 264 / 8; i += 512)
            *(bf16x8*)&Hl[i * 8] = z;
    }
    __syncthreads();

    float c_reg[2][2][4] = {};

    for (int s = 1; s <= 100; ++s) {
        // ---- prefetch additive slab for s+1 (issued before MFMAs) ----
        const unsigned short* psrc =
            (s <= 49) ? xw + ((size_t)s * BATCH + r0) * NG + cg * 128 :
            (s == 50) ? l0wb + (size_t)r0 * NG + cg * 128 : nullptr;
        bf16x8 pf0, pf1;
        if (psrc) {
            const int c0 = tid, c1 = tid + 512;
            pf0 = *(const bf16x8*)&psrc[(size_t)(c0 >> 4) * NG + (c0 & 15) * 8];
            pf1 = *(const bf16x8*)&psrc[(size_t)(c1 >> 4) * NG + (c1 & 15) * 8];
        }

        // ---- K loop: h(LDS) x W(LDS-resident) ----
        f32x4 acc[2][2] = {};
        #pragma unroll
        for (int kf = 0; kf < 8; ++kf) {
            bf16x8 a0 = *(const bf16x8*)&Hl[(wm * 32 +      l15) * 264 + kf * 32 + lhi * 8];
            bf16x8 a1 = *(const bf16x8*)&Hl[(wm * 32 + 16 + l15) * 264 + kf * 32 + lhi * 8];
            bf16x8 b0 = *(const bf16x8*)&Wl[(((wn * 2 + 0) * 8 + kf) * 64 + lane) * 8];
            bf16x8 b1 = *(const bf16x8*)&Wl[(((wn * 2 + 1) * 8 + kf) * 64 + lane) * 8];
            acc[0][0] = __builtin_amdgcn_mfma_f32_16x16x32_bf16(a0, b0, acc[0][0], 0, 0, 0);
            acc[0][1] = __builtin_amdgcn_mfma_f32_16x16x32_bf16(a0, b1, acc[0][1], 0, 0, 0);
            acc[1][0] = __builtin_amdgcn_mfma_f32_16x16x32_bf16(a1, b0, acc[1][0], 0, 0, 0);
            acc[1][1] = __builtin_amdgcn_mfma_f32_16x16x32_bf16(a1, b1, acc[1][1], 0, 0, 0);
        }

        if (psrc) {   // land prefetch into the inactive Xl buffer
            const int xb = (s + 1) & 1;
            const int c0 = tid, c1 = tid + 512;
            *(bf16x8*)&Xl[xb * 8192 + (c0 >> 4) * 128 + (c0 & 15) * 8] = pf0;
            *(bf16x8*)&Xl[xb * 8192 + (c1 >> 4) * 128 + (c1 & 15) * 8] = pf1;
        }

        // ---- epilogue: additive + fused cell + h write ----
        const int mode = (s <= 50) ? 0 : (s == 51) ? 1 : 2;
        unsigned short* hdst = (s <= 50) ? hpp + (size_t)(s & 1) * SLAB
                                         : hdec + (size_t)(s - 51) * SLAB;
        const int xb = s & 1;
        #pragma unroll
        for (int mi = 0; mi < 2; ++mi)
            #pragma unroll
            for (int ni = 0; ni < 2; ++ni)
                #pragma unroll
                for (int r = 0; r < 4; ++r) {
                    const int rw = wm * 32 + mi * 16 + lhi * 4 + r;
                    float v = acc[mi][ni][r];
                    if (mode <= 1)
                        v += b2f(Xl[xb * 8192 + rw * 128 + wn * 32 + ni * 16 + l15]);
                    if (mode >= 1)
                        v += ((mode == 2) ? bf_r[ni] : 0.f)
                           + cmdl[rw][0] * w0_r[ni] + cmdl[rw][1] * w1_r[ni];
                    float act = (g == 2) ? tanhfa(v) : sigf(v);
                    float a1 = __shfl_xor(act, 1);
                    float a2 = __shfl_xor(act, 2);
                    float a3 = __shfl_xor(act, 3);
                    if (g == 0) {                    // lane holds i; a1=f a2=g a3=o
                        float cc = a1 * c_reg[mi][ni][r] + act * a2;
                        c_reg[mi][ni][r] = cc;
                        const int u = cg * 32 + wn * 8 + ni * 4 + (l15 >> 2);
                        hdst[(size_t)(r0 + rw) * HN + u] = f2b(a3 * tanhfa(cc));
                    }
                }

        // ---- signal: stores drained per wave, one release per block ----
        __threadfence_block();
        __syncthreads();
        if (tid == 0)
            __hip_atomic_store(&myflags[cg], s, __ATOMIC_RELEASE, __HIP_MEMORY_SCOPE_AGENT);
        if (s == 100) break;

        // ---- wait for the 8 peers of this row-group (all threads poll) ----
        while (__hip_atomic_load(&myflags[tid & 7], __ATOMIC_ACQUIRE,
                                 __HIP_MEMORY_SCOPE_AGENT) < s)
            __builtin_amdgcn_s_sleep(1);
        __syncthreads();

        // ---- stage for step s+1 ----
        if (s == 50) {
            const unsigned short* src = Wf_dec0 + (size_t)cg * 32768;
            #pragma unroll
            for (int i = 0; i < 8; ++i) {
                const int c = i * 512 + tid;
                *(bf16x8*)&Wl[c * 8] = *(const bf16x8*)&src[c * 8];
            }
        } else if (s == 51) {
            const unsigned short* src = Wf_dec + (size_t)cg * 32768;
            #pragma unroll
            for (int i = 0; i < 8; ++i) {
                const int c = i * 512 + tid;
                *(bf16x8*)&Wl[c * 8] = *(const bf16x8*)&src[c * 8];
            }
        }
        const unsigned short* hsrc = (s <= 50) ? hpp + (size_t)(s & 1) * SLAB
                                               : hdec + (size_t)(s - 51) * SLAB;
        #pragma unroll
        for (int i = 0; i < 4; ++i) {
            const int row = (tid >> 5) + i * 16;
            const int o = (tid & 31) * 8;
            *(bf16x8*)&Hl[row * 264 + o] =
                *(const bf16x8*)&hsrc[(size_t)(r0 + row) * HN + o];
        }
        if (s >= 50 && tid < 64) {   // cmd slab for step s+1 (t = s-50)
            const float2 cv = *(const float2*)
                &cmds[(size_t)(r0 + tid) * (TN * CMDN) + (s - 50) * CMDN];
            cmdl[tid][0] = cv.x; cmdl[tid][1] = cv.y;
        }
        __syncthreads();
    }
}

// ---------------------------------------------------------------------------
// Packs / folds (one-time)
// ---------------------------------------------------------------------------
__global__ __launch_bounds__(256) void pack_w(
    const float* __restrict__ past,
    const float* __restrict__ eWih, const float* __restrict__ eb,
    const float* __restrict__ dWih, const float* __restrict__ db,
    const float* __restrict__ oW,
    unsigned short* __restrict__ L0b,      // [2048][384]
    unsigned short* __restrict__ Wihe_p,   // [1024][384] p-order
    unsigned short* __restrict__ Wdihl_p,  // [1024][384] p-order
    unsigned short* __restrict__ oWp,      // [384][256]
    float* __restrict__ Wc_p,              // [1024][2]
    float* __restrict__ ebp, float* __restrict__ dbp)
{
    int idx = blockIdx.x * 256 + threadIdx.x;
    if (idx < BATCH * KP) {                // L0b: lidar0 = past[:, -1, 2:]
        int b = idx / KP, k = idx - b * KP;
        L0b[idx] = (k < LIDARN)
            ? f2b(past[((size_t)b * TN + (TN - 1)) * KXN + CMDN + k]) : (unsigned short)0;
    }
    if (idx < NG * KP) {
        int p = idx / KP, k = idx - p * KP;
        int j = p2j(p);
        Wihe_p[idx]  = (k < KXN)    ? f2b(eWih[(size_t)j * KXN + k]) : (unsigned short)0;
        Wdihl_p[idx] = (k < LIDARN) ? f2b(dWih[(size_t)j * KXN + k]) : (unsigned short)0;
        if (k < 2) Wc_p[p * 2 + k] = dWih[(size_t)j * KXN + LIDARN + k];
        if (k == 0) { ebp[p] = eb[j]; dbp[p] = db[j]; }
    }
    if (idx < KP * HN) {
        int n = idx / HN, k = idx - n * HN;
        oWp[idx] = (n < LIDARN) ? f2b(oW[(size_t)n * HN + k]) : (unsigned short)0;
    }
}

// Wcomb_f[p][k] = dWhh[j][k] + sum_n dWih[j][n] * oW[n][k]   (f32, p-order)
__global__ __launch_bounds__(256) void wcomb_kernel(
    const float* __restrict__ dWih, const float* __restrict__ dWhh,
    const float* __restrict__ oW, float* __restrict__ Wcomb_f)
{
    int p = blockIdx.x, k = threadIdx.x;
    int j = p2j(p);
    float s = dWhh[(size_t)j * HN + k];
    for (int n = 0; n < LIDARN; ++n)
        s += dWih[(size_t)j * KXN + n] * oW[(size_t)n * HN + k];
    Wcomb_f[(size_t)p * HN + k] = s;
}

// biasf[p] = db[j] + sum_n dWih[j][n] * ob[n]
__global__ __launch_bounds__(256) void biasf_kernel(
    const float* __restrict__ dWih, const float* __restrict__ db,
    const float* __restrict__ ob, float* __restrict__ biasf)
{
    int p = blockIdx.x * 256 + threadIdx.x;
    if (p >= NG) return;
    int j = p2j(p);
    float s = db[j];
    for (int n = 0; n < LIDARN; ++n)
        s += dWih[(size_t)j * KXN + n] * ob[n];
    biasf[p] = s;
}

// Fragment-pack three recurrence weights:
// dst[((cf*8+kf)*64+lane)*8+e] = src[col=cf*16+(lane&15)][k=kf*32+(lane>>4)*8+e]
__global__ __launch_bounds__(256) void pack_wfrag(
    const float* __restrict__ eWhh, const float* __restrict__ dWhh,
    const float* __restrict__ Wcomb_f,
    unsigned short* __restrict__ Wf_enc,
    unsigned short* __restrict__ Wf_dec0,
    unsigned short* __restrict__ Wf_dec)
{
    const int NW = NG * HN;                      // 262144
    int idx = blockIdx.x * 256 + threadIdx.x;
    if (idx >= 3 * NW) return;
    int sel = idx / NW;
    int d   = idx - sel * NW;
    int e    = d & 7;
    int lane = (d >> 3) & 63;
    int kf   = (d >> 9) & 7;
    int cf   = d >> 12;
    int p = cf * 16 + (lane & 15);
    int k = kf * 32 + (lane >> 4) * 8 + e;
    if (sel == 0)      Wf_enc[d]  = f2b(eWhh[(size_t)p2j(p) * HN + k]);
    else if (sel == 1) Wf_dec0[d] = f2b(dWhh[(size_t)p2j(p) * HN + k]);
    else               Wf_dec[d]  = f2b(Wcomb_f[(size_t)p * HN + k]);
}

__global__ __launch_bounds__(256) void init_flags(int* __restrict__ flags)
{
    int idx = blockIdx.x * 256 + threadIdx.x;
    if (idx < 32 * 8) flags[idx] = 0;
}

extern "C" void kernel_launch(void* const* d_in, const int* in_sizes, int n_in,
                              void* d_out, int out_size, void* d_ws, size_t ws_size,
                              hipStream_t stream)
{
    const float* past = (const float*)d_in[0];
    const float* cmds = (const float*)d_in[1];
    const float* eWih = (const float*)d_in[2];
    const float* eWhh = (const float*)d_in[3];
    const float* eb   = (const float*)d_in[4];
    const float* dWih = (const float*)d_in[5];
    const float* dWhh = (const float*)d_in[6];
    const float* db   = (const float*)d_in[7];
    const float* oW   = (const float*)d_in[8];
    const float* ob   = (const float*)d_in[9];
    float* out = (float*)d_out;

    char* w = (char*)d_ws;
    auto alloc = [&](size_t bytes) {
        char* p = w; w += (bytes + 255) & ~(size_t)255; return p;
    };
    unsigned short* xw      = (unsigned short*)alloc((size_t)MR * NG * 2);   // 209.7 MB
    unsigned short* hdec    = (unsigned short*)alloc((size_t)MR * HN * 2);   // 52.4 MB
    unsigned short* l0wb    = (unsigned short*)alloc((size_t)BATCH * NG * 2);// 4.2 MB
    unsigned short* hpp     = (unsigned short*)alloc(2 * SLAB * 2);          // 2 MB
    float*          Wcomb_f = (float*)alloc((size_t)NG * HN * 4);            // 1 MB
    unsigned short* Wf_enc  = (unsigned short*)alloc((size_t)NG * HN * 2);
    unsigned short* Wf_dec0 = (unsigned short*)alloc((size_t)NG * HN * 2);
    unsigned short* Wf_dec  = (unsigned short*)alloc((size_t)NG * HN * 2);
    unsigned short* L0b     = (unsigned short*)alloc((size_t)BATCH * KP * 2);
    unsigned short* Wihe_p  = (unsigned short*)alloc((size_t)NG * KP * 2);
    unsigned short* Wdihl_p = (unsigned short*)alloc((size_t)NG * KP * 2);
    unsigned short* oWp     = (unsigned short*)alloc((size_t)KP * HN * 2);
    float*          Wc_p    = (float*)alloc((size_t)NG * 2 * 4);
    float*          ebp     = (float*)alloc(NG * 4);
    float*          dbp     = (float*)alloc(NG * 4);
    float*          biasf   = (float*)alloc(NG * 4);
    int*            flags   = (int*)alloc(32 * 8 * 4);

    pack_w<<<(BATCH * KP + 255) / 256, 256, 0, stream>>>(
        past, eWih, eb, dWih, db, oW,
        L0b, Wihe_p, Wdihl_p, oWp, Wc_p, ebp, dbp);
    wcomb_kernel<<<NG, 256, 0, stream>>>(dWih, dWhh, oW, Wcomb_f);
    biasf_kernel<<<(NG + 255) / 256, 256, 0, stream>>>(dWih, db, ob, biasf);
    pack_wfrag<<<(3 * NG * HN + 255) / 256, 256, 0, stream>>>(
        eWhh, dWhh, Wcomb_f, Wf_enc, Wf_dec0, Wf_dec);
    init_flags<<<1, 256, 0, stream>>>(flags);

    // xw = pack(past) @ Wihe^T + eb  (fused A-pack, bf16 out, t-major rows)
    gemm128<2, 1><<<dim3(NG / 128, MR / 128), 256, 0, stream>>>(
        nullptr, past, Wihe_p, ebp, xw, KP, NG);
    // l0wb = lidar0 @ Wl^T + db (bf16 slab, same format as xw slabs)
    gemm128<2, 0><<<dim3(NG / 128, BATCH / 128), 256, 0, stream>>>(
        L0b, nullptr, Wdihl_p, dbp, l0wb, KP, NG);

    // all 100 recurrent steps: one cooperative kernel, per-rg flag barrier
    {
        const unsigned short* xw_c = xw;  const unsigned short* l0_c = l0wb;
        const float* biasf_c = biasf;     const float* cmdw_c = Wc_p;
        const float* cmds_c = cmds;
        const unsigned short* we = Wf_enc, *wd0 = Wf_dec0, *wd = Wf_dec;
        unsigned short* hpp_ = hpp; unsigned short* hd_ = hdec; int* fl_ = flags;
        void* args[] = {
            (void*)&xw_c, (void*)&l0_c, (void*)&biasf_c, (void*)&cmdw_c, (void*)&cmds_c,
            (void*)&we, (void*)&wd0, (void*)&wd,
            (void*)&hpp_, (void*)&hd_, (void*)&fl_
        };
        hipLaunchCooperativeKernel(reinterpret_cast<void*>(recur_flags),
                                   dim3(256), dim3(512), args, 0, stream);
    }

    // out[b][t][n] = hdec[t][b] @ oW^T + ob
    gemm128<1, 0><<<dim3(KP / 128, MR / 128), 256, 0, stream>>>(
        hdec, nullptr, oWp, ob, out, HN, 0);
}

// Round 9
// 1862.618 us; speedup vs baseline: 2.3202x; 2.3202x over previous
//
#include <hip/hip_runtime.h>
#include <hip/hip_bf16.h>
#include <math.h>

#define CMDN   2
#define LIDARN 360
#define HN     256
#define TN     50
#define BATCH  2048
#define KXN    362              // CMD+LIDAR
#define NG     1024             // 4*H gate columns
#define KP     384              // padded x-K for big GEMMs
#define MR     (TN*BATCH)       // 102400 rows (t-major: r = t*2048 + b)
#define SLAB   ((size_t)BATCH*HN)

typedef __attribute__((ext_vector_type(8))) short bf16x8;
typedef __attribute__((ext_vector_type(4))) float f32x4;

__device__ inline unsigned short f2b(float f) {
    unsigned int x = __builtin_bit_cast(unsigned int, f);
    x += 0x7FFFu + ((x >> 16) & 1u);
    return (unsigned short)(x >> 16);
}
__device__ inline float b2f(unsigned short u) {
    unsigned int x = ((unsigned int)u) << 16;
    return __builtin_bit_cast(float, x);
}
__device__ inline float sigf(float x)  { return 1.f / (1.f + __expf(-x)); }
__device__ inline float tanhfa(float x){ return 2.f / (1.f + __expf(-2.f * x)) - 1.f; }

// packed gate-col order: p = 4*u + g  ->  original row jorig = g*256 + u
__device__ inline int p2j(int p) { return ((p & 3) << 8) + (p >> 2); }

// ---------------------------------------------------------------------------
// 128x128 MFMA GEMM with chunked XCD swizzle (proven rounds 4-8).
// AMODE 0: A bf16 [M][K].  AMODE 1: A = past fp32 with (b,t) remap + zero-pad.
// OMODE 0: C f32 = acc+bias. OMODE 1: outproj remap to out[b][t][col], col<360.
// OMODE 2: C bf16 = acc+bias.
// ---------------------------------------------------------------------------
template<int OMODE, int AMODE>
__global__ __launch_bounds__(256) void gemm128(
    const unsigned short* __restrict__ A,
    const float* __restrict__ Af,
    const unsigned short* __restrict__ B,
    const float* __restrict__ bias,
    void* __restrict__ Cv,
    int K, int ldc)
{
    __shared__ __align__(16) unsigned short As[128][40];
    __shared__ __align__(16) unsigned short Bs[128][40];

    const int nwg = gridDim.x * gridDim.y;
    const int hid = blockIdx.y * gridDim.x + blockIdx.x;
    const int lid = (hid & 7) * (nwg >> 3) + (hid >> 3);
    const int bx  = lid % gridDim.x;
    const int by  = lid / gridDim.x;

    const int tid  = threadIdx.x;
    const int lane = tid & 63;
    const int wv   = tid >> 6;
    const int wm   = wv >> 1, wn = wv & 1;
    const int r0   = by * 128;
    const int n0   = bx * 128;
    const int l15  = lane & 15;
    const int kb   = (lane >> 4) << 3;
    const int row1 = tid >> 2, q1 = tid & 3;

    f32x4 acc[4][4] = {};

    for (int k0 = 0; k0 < K; k0 += 32) {
        if (AMODE == 0) {
            *(bf16x8*)&As[row1][q1 * 8] =
                *(const bf16x8*)&A[(size_t)(r0 + row1) * K + k0 + q1 * 8];
            *(bf16x8*)&As[row1 + 64][q1 * 8] =
                *(const bf16x8*)&A[(size_t)(r0 + row1 + 64) * K + k0 + q1 * 8];
        } else {
            #pragma unroll
            for (int hh = 0; hh < 2; ++hh) {
                const int r  = r0 + row1 + hh * 64;
                const int tt = r >> 11, bb = r & 2047;
                const float* p = Af + ((size_t)bb * TN + tt) * KXN;
                const int kbase = k0 + q1 * 8;
                bf16x8 v;
                if (kbase + 8 <= KXN) {
                    float2 f0 = *(const float2*)(p + kbase);
                    float2 f1 = *(const float2*)(p + kbase + 2);
                    float2 f2 = *(const float2*)(p + kbase + 4);
                    float2 f3 = *(const float2*)(p + kbase + 6);
                    v[0] = (short)f2b(f0.x); v[1] = (short)f2b(f0.y);
                    v[2] = (short)f2b(f1.x); v[3] = (short)f2b(f1.y);
                    v[4] = (short)f2b(f2.x); v[5] = (short)f2b(f2.y);
                    v[6] = (short)f2b(f3.x); v[7] = (short)f2b(f3.y);
                } else {
                    #pragma unroll
                    for (int e = 0; e < 8; ++e) {
                        int k = kbase + e;
                        v[e] = (k < KXN) ? (short)f2b(p[k]) : (short)0;
                    }
                }
                *(bf16x8*)&As[row1 + hh * 64][q1 * 8] = v;
            }
        }
        *(bf16x8*)&Bs[row1][q1 * 8] =
            *(const bf16x8*)&B[(size_t)(n0 + row1) * K + k0 + q1 * 8];
        *(bf16x8*)&Bs[row1 + 64][q1 * 8] =
            *(const bf16x8*)&B[(size_t)(n0 + row1 + 64) * K + k0 + q1 * 8];
        __syncthreads();
        bf16x8 a[4], b[4];
        #pragma unroll
        for (int i = 0; i < 4; ++i) {
            a[i] = *(const bf16x8*)&As[wm * 64 + i * 16 + l15][kb];
            b[i] = *(const bf16x8*)&Bs[wn * 64 + i * 16 + l15][kb];
        }
        #pragma unroll
        for (int mi = 0; mi < 4; ++mi)
            #pragma unroll
            for (int ni = 0; ni < 4; ++ni)
                acc[mi][ni] = __builtin_amdgcn_mfma_f32_16x16x32_bf16(a[mi], b[ni], acc[mi][ni], 0, 0, 0);
        __syncthreads();
    }

    #pragma unroll
    for (int mi = 0; mi < 4; ++mi) {
        const int rowb = r0 + wm * 64 + mi * 16 + ((lane >> 4) << 2);
        #pragma unroll
        for (int ni = 0; ni < 4; ++ni) {
            const int col = n0 + wn * 64 + ni * 16 + l15;
            #pragma unroll
            for (int r = 0; r < 4; ++r) {
                const int row = rowb + r;
                float v = acc[mi][ni][r];
                if (OMODE == 0) {
                    ((float*)Cv)[(size_t)row * ldc + col] = v + bias[col];
                } else if (OMODE == 2) {
                    ((unsigned short*)Cv)[(size_t)row * ldc + col] = f2b(v + bias[col]);
                } else {
                    if (col < LIDARN) {
                        int t = row >> 11, b = row & 2047;
                        ((float*)Cv)[(size_t)b * (TN * LIDARN) + (size_t)t * LIDARN + col] = v + bias[col];
                    }
                }
            }
        }
    }
}

// ---------------------------------------------------------------------------
// Recurrent step v2 (relaunch structure): 256 blocks x 256 threads.
// bid = cg*32 + rg  ->  bid%8 = rg%8: the 8 cg-peers of a row-group share an
// XCD (perf heuristic only; correctness comes from the kernel boundary).
// Block: 64 batch rows x 128 gate cols. h staged to LDS (coalesced, padded);
// W read directly from L2 in frag-packed order (no LDS, no extra barriers);
// additive slab (xw / l0wb) staged to LDS coalesced; c in global f32 (L2-hot).
// Wave w (0..3) owns cols [w*32, w*32+32) of the block's 128; 4 mf x 2 ni.
// MODE 0: enc (Xl = xw_t). MODE 1: dec0 (Xl = l0wb, + cmd). MODE 2: dec
// (biasf + cmd, W = Wcomb).
// ---------------------------------------------------------------------------
template<int MODE>
__global__ __launch_bounds__(256) void step2(
    const unsigned short* __restrict__ hsrc,   // [2048][256] bf16
    const unsigned short* __restrict__ Wf,     // frag-packed [64cf][8kf][64][8]
    const unsigned short* __restrict__ addb,   // MODE<=1: slab [2048][1024] bf16
    const float* __restrict__ biasf,           // MODE 2
    const float* __restrict__ cmdw,            // [1024][2]  (MODE>=1)
    const float* __restrict__ cmds_t,          // cmds + t*2 (MODE>=1), row stride 100
    float* __restrict__ cst,                   // [2048][256] f32
    unsigned short* __restrict__ hdst)         // [2048][256] bf16
{
    __shared__ __align__(16) unsigned short Hl[64 * 264];   // 33 KB, pad 256->264
    __shared__ __align__(16) unsigned short Xl[64 * 128];   // 16 KB
    __shared__ float cmdl[64][2];

    const int tid  = threadIdx.x;
    const int lane = tid & 63;
    const int w    = tid >> 6;            // wave 0..3
    const int l15  = lane & 15;
    const int lhi  = lane >> 4;
    const int g    = l15 & 3;             // 0=i 1=f 2=g 3=o
    const int cg   = blockIdx.x >> 5;     // 0..7
    const int rg   = blockIdx.x & 31;     // 0..31
    const int r0   = rg * 64;

    // ---- stage h (coalesced 16B) ----
    #pragma unroll
    for (int i = 0; i < 8; ++i) {
        const int c = i * 256 + tid;          // 0..2047
        const int row = c >> 5, col8 = c & 31;
        *(bf16x8*)&Hl[row * 264 + col8 * 8] =
            *(const bf16x8*)&hsrc[(size_t)(r0 + row) * HN + col8 * 8];
    }
    // ---- stage additive slab ----
    if (MODE <= 1) {
        const unsigned short* xs = addb + (size_t)r0 * NG + cg * 128;
        #pragma unroll
        for (int i = 0; i < 4; ++i) {
            const int c = i * 256 + tid;      // 0..1023
            const int row = c >> 4, col8 = c & 15;
            *(bf16x8*)&Xl[row * 128 + col8 * 8] =
                *(const bf16x8*)&xs[(size_t)row * NG + col8 * 8];
        }
    }
    if (MODE >= 1 && tid < 64) {
        const float2 cv = *(const float2*)&cmds_t[(size_t)(r0 + tid) * (TN * CMDN)];
        cmdl[tid][0] = cv.x; cmdl[tid][1] = cv.y;
    }
    __syncthreads();

    // ---- K loop: A from LDS, B direct from L2 (frag-packed) ----
    const unsigned short* wb = Wf + (size_t)(cg * 8 + w * 2) * 4096;  // cf stride 4096
    f32x4 acc[4][2] = {};
    #pragma unroll
    for (int kf = 0; kf < 8; ++kf) {
        bf16x8 b0 = *(const bf16x8*)&wb[(size_t)(kf * 64 + lane) * 8];
        bf16x8 b1 = *(const bf16x8*)&wb[(size_t)((8 + kf) * 64 + lane) * 8];
        #pragma unroll
        for (int mf = 0; mf < 4; ++mf) {
            bf16x8 a = *(const bf16x8*)&Hl[(mf * 16 + l15) * 264 + kf * 32 + lhi * 8];
            acc[mf][0] = __builtin_amdgcn_mfma_f32_16x16x32_bf16(a, b0, acc[mf][0], 0, 0, 0);
            acc[mf][1] = __builtin_amdgcn_mfma_f32_16x16x32_bf16(a, b1, acc[mf][1], 0, 0, 0);
        }
    }

    // ---- fused cell epilogue ----
    float w0_r[2], w1_r[2], bf_r[2];
    if (MODE >= 1) {
        #pragma unroll
        for (int ni = 0; ni < 2; ++ni) {
            const int p = cg * 128 + w * 32 + ni * 16 + l15;
            w0_r[ni] = cmdw[p * 2];
            w1_r[ni] = cmdw[p * 2 + 1];
            if (MODE == 2) bf_r[ni] = biasf[p];
        }
    }
    #pragma unroll
    for (int mf = 0; mf < 4; ++mf)
        #pragma unroll
        for (int ni = 0; ni < 2; ++ni)
            #pragma unroll
            for (int r = 0; r < 4; ++r) {
                const int rw = mf * 16 + lhi * 4 + r;
                float v = acc[mf][ni][r];
                if (MODE <= 1) v += b2f(Xl[rw * 128 + w * 32 + ni * 16 + l15]);
                if (MODE == 2) v += bf_r[ni];
                if (MODE >= 1) v += cmdl[rw][0] * w0_r[ni] + cmdl[rw][1] * w1_r[ni];
                float act = (g == 2) ? tanhfa(v) : sigf(v);
                float a1 = __shfl_xor(act, 1);
                float a2 = __shfl_xor(act, 2);
                float a3 = __shfl_xor(act, 3);
                if (g == 0) {                      // lane holds i; a1=f a2=g a3=o
                    const int u = cg * 32 + w * 8 + ni * 4 + (l15 >> 2);
                    const size_t idx = (size_t)(r0 + rw) * HN + u;
                    float cc = a1 * cst[idx] + act * a2;
                    cst[idx] = cc;
                    hdst[idx] = f2b(a3 * tanhfa(cc));
                }
            }
}

// ---------------------------------------------------------------------------
// Packs / folds (one-time)
// ---------------------------------------------------------------------------
__global__ __launch_bounds__(256) void pack_w(
    const float* __restrict__ past,
    const float* __restrict__ eWih, const float* __restrict__ eb,
    const float* __restrict__ dWih, const float* __restrict__ db,
    const float* __restrict__ oW,
    unsigned short* __restrict__ L0b,      // [2048][384]
    unsigned short* __restrict__ Wihe_p,   // [1024][384] p-order
    unsigned short* __restrict__ Wdihl_p,  // [1024][384] p-order
    unsigned short* __restrict__ oWp,      // [384][256]
    float* __restrict__ Wc_p,              // [1024][2]
    float* __restrict__ ebp, float* __restrict__ dbp)
{
    int idx = blockIdx.x * 256 + threadIdx.x;
    if (idx < BATCH * KP) {                // L0b: lidar0 = past[:, -1, 2:]
        int b = idx / KP, k = idx - b * KP;
        L0b[idx] = (k < LIDARN)
            ? f2b(past[((size_t)b * TN + (TN - 1)) * KXN + CMDN + k]) : (unsigned short)0;
    }
    if (idx < NG * KP) {
        int p = idx / KP, k = idx - p * KP;
        int j = p2j(p);
        Wihe_p[idx]  = (k < KXN)    ? f2b(eWih[(size_t)j * KXN + k]) : (unsigned short)0;
        Wdihl_p[idx] = (k < LIDARN) ? f2b(dWih[(size_t)j * KXN + k]) : (unsigned short)0;
        if (k < 2) Wc_p[p * 2 + k] = dWih[(size_t)j * KXN + LIDARN + k];
        if (k == 0) { ebp[p] = eb[j]; dbp[p] = db[j]; }
    }
    if (idx < KP * HN) {
        int n = idx / HN, k = idx - n * HN;
        oWp[idx] = (n < LIDARN) ? f2b(oW[(size_t)n * HN + k]) : (unsigned short)0;
    }
}

// Wcomb_f[p][k] = dWhh[j][k] + sum_n dWih[j][n] * oW[n][k]   (f32, p-order)
__global__ __launch_bounds__(256) void wcomb_kernel(
    const float* __restrict__ dWih, const float* __restrict__ dWhh,
    const float* __restrict__ oW, float* __restrict__ Wcomb_f)
{
    int p = blockIdx.x, k = threadIdx.x;
    int j = p2j(p);
    float s = dWhh[(size_t)j * HN + k];
    for (int n = 0; n < LIDARN; ++n)
        s += dWih[(size_t)j * KXN + n] * oW[(size_t)n * HN + k];
    Wcomb_f[(size_t)p * HN + k] = s;
}

// biasf[p] = db[j] + sum_n dWih[j][n] * ob[n]
__global__ __launch_bounds__(256) void biasf_kernel(
    const float* __restrict__ dWih, const float* __restrict__ db,
    const float* __restrict__ ob, float* __restrict__ biasf)
{
    int p = blockIdx.x * 256 + threadIdx.x;
    if (p >= NG) return;
    int j = p2j(p);
    float s = db[j];
    for (int n = 0; n < LIDARN; ++n)
        s += dWih[(size_t)j * KXN + n] * ob[n];
    biasf[p] = s;
}

// Fragment-pack three recurrence weights:
// dst[((cf*8+kf)*64+lane)*8+e] = src[col=cf*16+(lane&15)][k=kf*32+(lane>>4)*8+e]
__global__ __launch_bounds__(256) void pack_wfrag(
    const float* __restrict__ eWhh, const float* __restrict__ dWhh,
    const float* __restrict__ Wcomb_f,
    unsigned short* __restrict__ Wf_enc,
    unsigned short* __restrict__ Wf_dec0,
    unsigned short* __restrict__ Wf_dec)
{
    const int NW = NG * HN;                      // 262144
    int idx = blockIdx.x * 256 + threadIdx.x;
    if (idx >= 3 * NW) return;
    int sel = idx / NW;
    int d   = idx - sel * NW;
    int e    = d & 7;
    int lane = (d >> 3) & 63;
    int kf   = (d >> 9) & 7;
    int cf   = d >> 12;
    int p = cf * 16 + (lane & 15);
    int k = kf * 32 + (lane >> 4) * 8 + e;
    if (sel == 0)      Wf_enc[d]  = f2b(eWhh[(size_t)p2j(p) * HN + k]);
    else if (sel == 1) Wf_dec0[d] = f2b(dWhh[(size_t)p2j(p) * HN + k]);
    else               Wf_dec[d]  = f2b(Wcomb_f[(size_t)p * HN + k]);
}

// h0 = 0 (bf16), c = 0 (f32)
__global__ __launch_bounds__(256) void init_hc(
    unsigned short* __restrict__ h0, float* __restrict__ cst)
{
    int idx = blockIdx.x * 256 + threadIdx.x;
    if (idx < BATCH * HN) { h0[idx] = 0; cst[idx] = 0.f; }
}

extern "C" void kernel_launch(void* const* d_in, const int* in_sizes, int n_in,
                              void* d_out, int out_size, void* d_ws, size_t ws_size,
                              hipStream_t stream)
{
    const float* past = (const float*)d_in[0];
    const float* cmds = (const float*)d_in[1];
    const float* eWih = (const float*)d_in[2];
    const float* eWhh = (const float*)d_in[3];
    const float* eb   = (const float*)d_in[4];
    const float* dWih = (const float*)d_in[5];
    const float* dWhh = (const float*)d_in[6];
    const float* db   = (const float*)d_in[7];
    const float* oW   = (const float*)d_in[8];
    const float* ob   = (const float*)d_in[9];
    float* out = (float*)d_out;

    char* w = (char*)d_ws;
    auto alloc = [&](size_t bytes) {
        char* p = w; w += (bytes + 255) & ~(size_t)255; return p;
    };
    unsigned short* xw      = (unsigned short*)alloc((size_t)MR * NG * 2);   // 209.7 MB
    unsigned short* hdec    = (unsigned short*)alloc((size_t)MR * HN * 2);   // 52.4 MB
    unsigned short* l0wb    = (unsigned short*)alloc((size_t)BATCH * NG * 2);// 4.2 MB
    unsigned short* hpp     = (unsigned short*)alloc(2 * SLAB * 2);          // 2 MB
    float*          cst     = (float*)alloc(SLAB * 4);                       // 2 MB
    float*          Wcomb_f = (float*)alloc((size_t)NG * HN * 4);            // 1 MB
    unsigned short* Wf_enc  = (unsigned short*)alloc((size_t)NG * HN * 2);
    unsigned short* Wf_dec0 = (unsigned short*)alloc((size_t)NG * HN * 2);
    unsigned short* Wf_dec  = (unsigned short*)alloc((size_t)NG * HN * 2);
    unsigned short* L0b     = (unsigned short*)alloc((size_t)BATCH * KP * 2);
    unsigned short* Wihe_p  = (unsigned short*)alloc((size_t)NG * KP * 2);
    unsigned short* Wdihl_p = (unsigned short*)alloc((size_t)NG * KP * 2);
    unsigned short* oWp     = (unsigned short*)alloc((size_t)KP * HN * 2);
    float*          Wc_p    = (float*)alloc((size_t)NG * 2 * 4);
    float*          ebp     = (float*)alloc(NG * 4);
    float*          dbp     = (float*)alloc(NG * 4);
    float*          biasf   = (float*)alloc(NG * 4);

    pack_w<<<(BATCH * KP + 255) / 256, 256, 0, stream>>>(
        past, eWih, eb, dWih, db, oW,
        L0b, Wihe_p, Wdihl_p, oWp, Wc_p, ebp, dbp);
    wcomb_kernel<<<NG, 256, 0, stream>>>(dWih, dWhh, oW, Wcomb_f);
    biasf_kernel<<<(NG + 255) / 256, 256, 0, stream>>>(dWih, db, ob, biasf);
    pack_wfrag<<<(3 * NG * HN + 255) / 256, 256, 0, stream>>>(
        eWhh, dWhh, Wcomb_f, Wf_enc, Wf_dec0, Wf_dec);
    init_hc<<<(BATCH * HN + 255) / 256, 256, 0, stream>>>(hpp, cst);

    // xw = pack(past) @ Wihe^T + eb  (fused A-pack, bf16 out, t-major rows)
    gemm128<2, 1><<<dim3(NG / 128, MR / 128), 256, 0, stream>>>(
        nullptr, past, Wihe_p, ebp, xw, KP, NG);
    // l0wb = lidar0 @ Wl^T + db (bf16 slab, same layout as xw slabs)
    gemm128<2, 0><<<dim3(NG / 128, BATCH / 128), 256, 0, stream>>>(
        L0b, nullptr, Wdihl_p, dbp, l0wb, KP, NG);

    // ---- encoder: 50 relaunched steps, h ping-pong in hpp ----
    for (int t = 0; t < TN; ++t) {
        const unsigned short* hs = hpp + (size_t)(t & 1) * SLAB;
        unsigned short*       hd = hpp + (size_t)((t + 1) & 1) * SLAB;
        step2<0><<<256, 256, 0, stream>>>(
            hs, Wf_enc, xw + (size_t)t * BATCH * NG,
            nullptr, nullptr, nullptr, cst, hd);
    }
    // ---- decoder step 0 (additive = l0wb + cmd), h -> hdec[0] ----
    step2<1><<<256, 256, 0, stream>>>(
        hpp + (size_t)(TN & 1) * SLAB, Wf_dec0, l0wb,
        nullptr, Wc_p, cmds, cst, hdec);
    // ---- decoder steps 1..49 (folded recurrence) ----
    for (int t = 1; t < TN; ++t) {
        step2<2><<<256, 256, 0, stream>>>(
            hdec + (size_t)(t - 1) * SLAB, Wf_dec, nullptr,
            biasf, Wc_p, cmds + (size_t)t * CMDN, cst,
            hdec + (size_t)t * SLAB);
    }

    // out[b][t][n] = hdec[t][b] @ oW^T + ob
    gemm128<1, 0><<<dim3(KP / 128, MR / 128), 256, 0, stream>>>(
        hdec, nullptr, oWp, ob, out, HN, 0);
}

// Round 10
// 1368.173 us; speedup vs baseline: 3.1587x; 1.3614x over previous
//
#include <hip/hip_runtime.h>
#include <hip/hip_bf16.h>
#include <math.h>

#define CMDN   2
#define LIDARN 360
#define HN     256
#define TN     50
#define BATCH  2048
#define KXN    362              // CMD+LIDAR
#define NG     1024             // 4*H gate columns
#define KP     384              // padded x-K for big GEMMs
#define MR     (TN*BATCH)       // 102400 rows (t-major: r = t*2048 + b)
#define SLAB   ((size_t)BATCH*HN)
#define NOF    24               // out col fragments (24*16 = 384 >= 360)

typedef __attribute__((ext_vector_type(8))) short bf16x8;
typedef __attribute__((ext_vector_type(4))) float f32x4;

__device__ inline unsigned short f2b(float f) {
    unsigned int x = __builtin_bit_cast(unsigned int, f);
    x += 0x7FFFu + ((x >> 16) & 1u);
    return (unsigned short)(x >> 16);
}
__device__ inline float b2f(unsigned short u) {
    unsigned int x = ((unsigned int)u) << 16;
    return __builtin_bit_cast(float, x);
}
__device__ inline float sigf(float x)  { return 1.f / (1.f + __expf(-x)); }
__device__ inline float tanhfa(float x){ return 2.f / (1.f + __expf(-2.f * x)) - 1.f; }

// packed gate-col order: p = 4*u + g  ->  original row jorig = g*256 + u
__device__ inline int p2j(int p) { return ((p & 3) << 8) + (p >> 2); }

typedef const __attribute__((address_space(1))) unsigned int* gp1_t;
typedef __attribute__((address_space(3))) unsigned int* lp3_t;
__device__ inline void gload16(const void* g, void* l) {
    __builtin_amdgcn_global_load_lds((gp1_t)g, (lp3_t)l, 16, 0, 0);
}

// ---------------------------------------------------------------------------
// Pack past fp32 -> Xb bf16 [MR][KP] t-major (r = t*2048 + b), zero-padded.
// ---------------------------------------------------------------------------
__global__ __launch_bounds__(256) void pack_xb(
    const float* __restrict__ past, unsigned short* __restrict__ Xb)
{
    int c = blockIdx.x * 256 + threadIdx.x;      // chunk of 8 elems
    if (c >= MR * (KP / 8)) return;
    int r = c / (KP / 8), kc = c - r * (KP / 8);
    int b = r & 2047, t = r >> 11;
    const float* p = past + ((size_t)b * TN + t) * KXN;
    const int k = kc * 8;
    bf16x8 v;
    if (k + 8 <= KXN) {
        float2 f0 = *(const float2*)(p + k);
        float2 f1 = *(const float2*)(p + k + 2);
        float2 f2 = *(const float2*)(p + k + 4);
        float2 f3 = *(const float2*)(p + k + 6);
        v[0] = (short)f2b(f0.x); v[1] = (short)f2b(f0.y);
        v[2] = (short)f2b(f1.x); v[3] = (short)f2b(f1.y);
        v[4] = (short)f2b(f2.x); v[5] = (short)f2b(f2.y);
        v[6] = (short)f2b(f3.x); v[7] = (short)f2b(f3.y);
    } else {
        #pragma unroll
        for (int e = 0; e < 8; ++e)
            v[e] = (k + e < KXN) ? (short)f2b(p[k + e]) : (short)0;
    }
    *(bf16x8*)&Xb[(size_t)r * KP + k] = v;
}

// ---------------------------------------------------------------------------
// 128x128 MFMA GEMM, global_load_lds(16B) staging, XOR-swizzled source +
// swizzled ds_read (linear LDS dest, rule both-sides-or-neither).
// A [M][K] bf16, B [N][K] bf16. Chunked XCD swizzle (nwg % 8 == 0).
// OMODE 0: C f32 = acc+bias. OMODE 2: C bf16 = acc+bias.
// OMODE 3: tail outproj: out[row][TN-1][col] = acc+ob[col], col<360.
// ---------------------------------------------------------------------------
template<int OMODE>
__global__ __launch_bounds__(256) void gemm_fast(
    const unsigned short* __restrict__ A,
    const unsigned short* __restrict__ B,
    const float* __restrict__ bias,
    void* __restrict__ Cv, int K, int ldc)
{
    __shared__ __align__(16) unsigned short As[128 * 32];
    __shared__ __align__(16) unsigned short Bs[128 * 32];

    const int nwg = gridDim.x * gridDim.y;
    const int hid = blockIdx.y * gridDim.x + blockIdx.x;
    const int lid = (hid & 7) * (nwg >> 3) + (hid >> 3);
    const int bx  = lid % gridDim.x;
    const int by  = lid / gridDim.x;

    const int tid  = threadIdx.x;
    const int lane = tid & 63;
    const int wv   = tid >> 6;
    const int wm   = wv >> 1, wn = wv & 1;
    const int r0   = by * 128;
    const int n0   = bx * 128;
    const int l15  = lane & 15;
    const int lhi  = lane >> 4;

    // staging geometry: wave wv, sub-chunk j -> LDS rows (wv*2+j)*16..+15
    const int srow = lane >> 2;          // 0..15 within chunk
    const int sc   = lane & 3;           // 16B chunk within 64B row

    f32x4 acc[4][4] = {};

    for (int k0 = 0; k0 < K; k0 += 32) {
        #pragma unroll
        for (int j = 0; j < 2; ++j) {
            const int rl = (wv * 2 + j) * 16 + srow;        // LDS row 0..127
            const int cs = sc ^ (rl & 3);                    // swizzled src chunk
            gload16(&A[(size_t)(r0 + rl) * K + k0 + cs * 8], &As[(wv * 2 + j) * 512]);
            gload16(&B[(size_t)(n0 + rl) * K + k0 + cs * 8], &Bs[(wv * 2 + j) * 512]);
        }
        __syncthreads();
        bf16x8 a[4], b[4];
        #pragma unroll
        for (int i = 0; i < 4; ++i) {
            const int ra = wm * 64 + i * 16 + l15;
            const int rb = wn * 64 + i * 16 + l15;
            a[i] = *(const bf16x8*)&As[ra * 32 + (lhi ^ (ra & 3)) * 8];
            b[i] = *(const bf16x8*)&Bs[rb * 32 + (lhi ^ (rb & 3)) * 8];
        }
        #pragma unroll
        for (int mi = 0; mi < 4; ++mi)
            #pragma unroll
            for (int ni = 0; ni < 4; ++ni)
                acc[mi][ni] = __builtin_amdgcn_mfma_f32_16x16x32_bf16(a[mi], b[ni], acc[mi][ni], 0, 0, 0);
        __syncthreads();
    }

    #pragma unroll
    for (int mi = 0; mi < 4; ++mi) {
        const int rowb = r0 + wm * 64 + mi * 16 + ((lane >> 4) << 2);
        #pragma unroll
        for (int ni = 0; ni < 4; ++ni) {
            const int col = n0 + wn * 64 + ni * 16 + l15;
            #pragma unroll
            for (int r = 0; r < 4; ++r) {
                const int row = rowb + r;
                float v = acc[mi][ni][r];
                if (OMODE == 0) {
                    ((float*)Cv)[(size_t)row * ldc + col] = v + bias[col];
                } else if (OMODE == 2) {
                    ((unsigned short*)Cv)[(size_t)row * ldc + col] = f2b(v + bias[col]);
                } else {
                    if (col < LIDARN)
                        ((float*)Cv)[(size_t)row * (TN * LIDARN) + (size_t)(TN - 1) * LIDARN + col]
                            = v + bias[col];
                }
            }
        }
    }
}

// ---------------------------------------------------------------------------
// Recurrent step v3: 256 blocks x 512 threads (8 waves -> 2 waves/SIMD).
// bid = cg*32 + rg. Block: 64 batch rows x 128 gate cols; wave owns 16 cols.
// h staged to LDS (padded 264); W direct from L2 (frag-packed); additive slab
// in LDS; c in global f32. MODE 2 additionally FUSES the outproj of the
// staged h (= h_{t-1}) -> out[:, t_prev, :] slice (48 cols per block).
// ---------------------------------------------------------------------------
template<int MODE>
__global__ __launch_bounds__(512) void step3(
    const unsigned short* __restrict__ hsrc,   // [2048][256] bf16
    const unsigned short* __restrict__ Wf,     // frag-packed [64cf][8kf][64][8]
    const unsigned short* __restrict__ addb,   // MODE<=1: slab [2048][1024] bf16
    const float* __restrict__ biasf,           // MODE 2
    const float* __restrict__ cmdw,            // [1024][2]  (MODE>=1)
    const float* __restrict__ cmds_t,          // cmds + t*2 (MODE>=1), row stride 100
    const unsigned short* __restrict__ oWf,    // MODE 2: frag-packed [24f][8kf][64][8]
    const float* __restrict__ ob,              // MODE 2
    float* __restrict__ out,                   // MODE 2: [2048][50][360] f32
    int tprev,                                 // MODE 2: time index for out
    float* __restrict__ cst,                   // [2048][256] f32
    unsigned short* __restrict__ hdst)         // [2048][256] bf16
{
    __shared__ __align__(16) unsigned short Hl[64 * 264];   // 33 KB
    __shared__ __align__(16) unsigned short Xl[64 * 128];   // 16 KB
    __shared__ float cmdl[64][2];

    const int tid  = threadIdx.x;
    const int lane = tid & 63;
    const int w    = tid >> 6;            // wave 0..7
    const int l15  = lane & 15;
    const int lhi  = lane >> 4;
    const int g    = l15 & 3;             // 0=i 1=f 2=g 3=o
    const int cg   = blockIdx.x >> 5;     // 0..7
    const int rg   = blockIdx.x & 31;     // 0..31
    const int r0   = rg * 64;

    // ---- stage h (coalesced 16B) ----
    #pragma unroll
    for (int i = 0; i < 4; ++i) {
        const int c = i * 512 + tid;          // 0..2047
        const int row = c >> 5, col8 = c & 31;
        *(bf16x8*)&Hl[row * 264 + col8 * 8] =
            *(const bf16x8*)&hsrc[(size_t)(r0 + row) * HN + col8 * 8];
    }
    // ---- stage additive slab ----
    if (MODE <= 1) {
        const unsigned short* xs = addb + (size_t)r0 * NG + cg * 128;
        #pragma unroll
        for (int i = 0; i < 2; ++i) {
            const int c = i * 512 + tid;      // 0..1023
            const int row = c >> 4, col8 = c & 15;
            *(bf16x8*)&Xl[row * 128 + col8 * 8] =
                *(const bf16x8*)&xs[(size_t)row * NG + col8 * 8];
        }
    }
    if (MODE >= 1 && tid < 64) {
        const float2 cv = *(const float2*)&cmds_t[(size_t)(r0 + tid) * (TN * CMDN)];
        cmdl[tid][0] = cv.x; cmdl[tid][1] = cv.y;
    }
    __syncthreads();

    // ---- gates K loop: A from LDS, B direct from L2 (frag-packed) ----
    const unsigned short* wb = Wf + (size_t)(cg * 8 + w) * 4096;  // cf stride 8kf*512
    f32x4 acc[4] = {};
    #pragma unroll
    for (int kf = 0; kf < 8; ++kf) {
        bf16x8 b = *(const bf16x8*)&wb[(size_t)(kf * 64 + lane) * 8];
        #pragma unroll
        for (int mf = 0; mf < 4; ++mf) {
            bf16x8 a = *(const bf16x8*)&Hl[(mf * 16 + l15) * 264 + kf * 32 + lhi * 8];
            acc[mf] = __builtin_amdgcn_mfma_f32_16x16x32_bf16(a, b, acc[mf], 0, 0, 0);
        }
    }

    // ---- fused outproj of staged h (MODE 2): wave w -> row strip w>>1,
    //      frags {0,1} (even w) or {2} (odd w) of the block's 3 col-frags ----
    f32x4 acc_o0 = {}, acc_o1 = {};
    const int mf_o = w >> 1;
    const int nf0  = (w & 1) ? 2 : 0;
    const int nfn  = (w & 1) ? 1 : 2;
    if (MODE == 2) {
        #pragma unroll
        for (int kf = 0; kf < 8; ++kf) {
            bf16x8 a = *(const bf16x8*)&Hl[(mf_o * 16 + l15) * 264 + kf * 32 + lhi * 8];
            const int f0 = cg * 3 + nf0;
            bf16x8 b0 = *(const bf16x8*)&oWf[(size_t)((f0 * 8 + kf) * 64 + lane) * 8];
            acc_o0 = __builtin_amdgcn_mfma_f32_16x16x32_bf16(a, b0, acc_o0, 0, 0, 0);
            if (nfn == 2) {
                bf16x8 b1 = *(const bf16x8*)&oWf[(size_t)(((f0 + 1) * 8 + kf) * 64 + lane) * 8];
                acc_o1 = __builtin_amdgcn_mfma_f32_16x16x32_bf16(a, b1, acc_o1, 0, 0, 0);
            }
        }
    }

    // ---- fused cell epilogue ----
    const int p = cg * 128 + w * 16 + l15;
    const int u = cg * 32 + w * 4 + (l15 >> 2);
    float w0_r = 0.f, w1_r = 0.f, bf_r = 0.f;
    if (MODE >= 1) { w0_r = cmdw[p * 2]; w1_r = cmdw[p * 2 + 1]; }
    if (MODE == 2) bf_r = biasf[p];
    #pragma unroll
    for (int mf = 0; mf < 4; ++mf)
        #pragma unroll
        for (int r = 0; r < 4; ++r) {
            const int rw = mf * 16 + lhi * 4 + r;
            float v = acc[mf][r];
            if (MODE <= 1) v += b2f(Xl[rw * 128 + w * 16 + l15]);
            if (MODE == 2) v += bf_r;
            if (MODE >= 1) v += cmdl[rw][0] * w0_r + cmdl[rw][1] * w1_r;
            float act = (g == 2) ? tanhfa(v) : sigf(v);
            float a1 = __shfl_xor(act, 1);
            float a2 = __shfl_xor(act, 2);
            float a3 = __shfl_xor(act, 3);
            if (g == 0) {                      // lane holds i; a1=f a2=g a3=o
                const size_t idx = (size_t)(r0 + rw) * HN + u;
                float cc = a1 * cst[idx] + act * a2;
                cst[idx] = cc;
                hdst[idx] = f2b(a3 * tanhfa(cc));
            }
        }

    // ---- out slice store (MODE 2) ----
    if (MODE == 2) {
        #pragma unroll
        for (int i = 0; i < 2; ++i) {
            if (i < nfn) {
                const int col = (cg * 3 + nf0 + i) * 16 + l15;
                if (col < LIDARN) {
                    const float bo = ob[col];
                    const f32x4 ao = i ? acc_o1 : acc_o0;
                    #pragma unroll
                    for (int r = 0; r < 4; ++r) {
                        const int brow = r0 + mf_o * 16 + lhi * 4 + r;
                        out[(size_t)brow * (TN * LIDARN) + (size_t)tprev * LIDARN + col]
                            = ao[r] + bo;
                    }
                }
            }
        }
    }
}

// ---------------------------------------------------------------------------
// Packs / folds (one-time)
// ---------------------------------------------------------------------------
__global__ __launch_bounds__(256) void pack_w(
    const float* __restrict__ past,
    const float* __restrict__ eWih, const float* __restrict__ eb,
    const float* __restrict__ dWih, const float* __restrict__ db,
    const float* __restrict__ oW,
    unsigned short* __restrict__ L0b,      // [2048][384]
    unsigned short* __restrict__ Wihe_p,   // [1024][384] p-order
    unsigned short* __restrict__ Wdihl_p,  // [1024][384] p-order
    unsigned short* __restrict__ oWp,      // [384][256]
    float* __restrict__ Wc_p,              // [1024][2]
    float* __restrict__ ebp, float* __restrict__ dbp)
{
    int idx = blockIdx.x * 256 + threadIdx.x;
    if (idx < BATCH * KP) {                // L0b: lidar0 = past[:, -1, 2:]
        int b = idx / KP, k = idx - b * KP;
        L0b[idx] = (k < LIDARN)
            ? f2b(past[((size_t)b * TN + (TN - 1)) * KXN + CMDN + k]) : (unsigned short)0;
    }
    if (idx < NG * KP) {
        int p = idx / KP, k = idx - p * KP;
        int j = p2j(p);
        Wihe_p[idx]  = (k < KXN)    ? f2b(eWih[(size_t)j * KXN + k]) : (unsigned short)0;
        Wdihl_p[idx] = (k < LIDARN) ? f2b(dWih[(size_t)j * KXN + k]) : (unsigned short)0;
        if (k < 2) Wc_p[p * 2 + k] = dWih[(size_t)j * KXN + LIDARN + k];
        if (k == 0) { ebp[p] = eb[j]; dbp[p] = db[j]; }
    }
    if (idx < KP * HN) {
        int n = idx / HN, k = idx - n * HN;
        oWp[idx] = (n < LIDARN) ? f2b(oW[(size_t)n * HN + k]) : (unsigned short)0;
    }
}

// Wcomb_f[p][k] = dWhh[j][k] + sum_n dWih[j][n] * oW[n][k]; 4 p per block.
__global__ __launch_bounds__(256) void wcomb_kernel(
    const float* __restrict__ dWih, const float* __restrict__ dWhh,
    const float* __restrict__ oW, float* __restrict__ Wcomb_f)
{
    const int pb = blockIdx.x * 4, k = threadIdx.x;
    int j0 = p2j(pb), j1 = p2j(pb + 1), j2 = p2j(pb + 2), j3 = p2j(pb + 3);
    float s0 = dWhh[(size_t)j0 * HN + k];
    float s1 = dWhh[(size_t)j1 * HN + k];
    float s2 = dWhh[(size_t)j2 * HN + k];
    float s3 = dWhh[(size_t)j3 * HN + k];
    #pragma unroll 4
    for (int n = 0; n < LIDARN; ++n) {
        const float ow = oW[(size_t)n * HN + k];
        s0 += dWih[(size_t)j0 * KXN + n] * ow;
        s1 += dWih[(size_t)j1 * KXN + n] * ow;
        s2 += dWih[(size_t)j2 * KXN + n] * ow;
        s3 += dWih[(size_t)j3 * KXN + n] * ow;
    }
    Wcomb_f[(size_t)pb * HN + k]            = s0;
    Wcomb_f[(size_t)(pb + 1) * HN + k]      = s1;
    Wcomb_f[(size_t)(pb + 2) * HN + k]      = s2;
    Wcomb_f[(size_t)(pb + 3) * HN + k]      = s3;
}

// biasf[p] = db[j] + sum_n dWih[j][n] * ob[n]
__global__ __launch_bounds__(256) void biasf_kernel(
    const float* __restrict__ dWih, const float* __restrict__ db,
    const float* __restrict__ ob, float* __restrict__ biasf)
{
    int p = blockIdx.x * 256 + threadIdx.x;
    if (p >= NG) return;
    int j = p2j(p);
    float s = db[j];
    for (int n = 0; n < LIDARN; ++n)
        s += dWih[(size_t)j * KXN + n] * ob[n];
    biasf[p] = s;
}

// Fragment-pack three recurrence weights.
__global__ __launch_bounds__(256) void pack_wfrag(
    const float* __restrict__ eWhh, const float* __restrict__ dWhh,
    const float* __restrict__ Wcomb_f,
    unsigned short* __restrict__ Wf_enc,
    unsigned short* __restrict__ Wf_dec0,
    unsigned short* __restrict__ Wf_dec)
{
    const int NW = NG * HN;                      // 262144
    int idx = blockIdx.x * 256 + threadIdx.x;
    if (idx >= 3 * NW) return;
    int sel = idx / NW;
    int d   = idx - sel * NW;
    int e    = d & 7;
    int lane = (d >> 3) & 63;
    int kf   = (d >> 9) & 7;
    int cf   = d >> 12;
    int p = cf * 16 + (lane & 15);
    int k = kf * 32 + (lane >> 4) * 8 + e;
    if (sel == 0)      Wf_enc[d]  = f2b(eWhh[(size_t)p2j(p) * HN + k]);
    else if (sel == 1) Wf_dec0[d] = f2b(dWhh[(size_t)p2j(p) * HN + k]);
    else               Wf_dec[d]  = f2b(Wcomb_f[(size_t)p * HN + k]);
}

// Fragment-pack outproj weights: 24 col-frags, rows >= 360 zero.
__global__ __launch_bounds__(256) void pack_owf(
    const float* __restrict__ oW, unsigned short* __restrict__ oWf)
{
    int d = blockIdx.x * 256 + threadIdx.x;
    if (d >= NOF * 8 * 64 * 8) return;           // 98304
    int e = d & 7, lane = (d >> 3) & 63, kf = (d >> 9) & 7, f = d >> 12;
    int n = f * 16 + (lane & 15);
    int k = kf * 32 + (lane >> 4) * 8 + e;
    oWf[d] = (n < LIDARN) ? f2b(oW[(size_t)n * HN + k]) : (unsigned short)0;
}

// h0 = 0 (bf16), c = 0 (f32)
__global__ __launch_bounds__(256) void init_hc(
    unsigned short* __restrict__ h0, float* __restrict__ cst)
{
    int idx = blockIdx.x * 256 + threadIdx.x;
    if (idx < BATCH * HN) { h0[idx] = 0; cst[idx] = 0.f; }
}

extern "C" void kernel_launch(void* const* d_in, const int* in_sizes, int n_in,
                              void* d_out, int out_size, void* d_ws, size_t ws_size,
                              hipStream_t stream)
{
    const float* past = (const float*)d_in[0];
    const float* cmds = (const float*)d_in[1];
    const float* eWih = (const float*)d_in[2];
    const float* eWhh = (const float*)d_in[3];
    const float* eb   = (const float*)d_in[4];
    const float* dWih = (const float*)d_in[5];
    const float* dWhh = (const float*)d_in[6];
    const float* db   = (const float*)d_in[7];
    const float* oW   = (const float*)d_in[8];
    const float* ob   = (const float*)d_in[9];
    float* out = (float*)d_out;

    char* w = (char*)d_ws;
    auto alloc = [&](size_t bytes) {
        char* p = w; w += (bytes + 255) & ~(size_t)255; return p;
    };
    unsigned short* xw      = (unsigned short*)alloc((size_t)MR * NG * 2);   // 209.7 MB
    unsigned short* Xb      = (unsigned short*)alloc((size_t)MR * KP * 2);   // 78.6 MB
    unsigned short* hdec    = (unsigned short*)alloc((size_t)MR * HN * 2);   // 52.4 MB
    unsigned short* l0wb    = (unsigned short*)alloc((size_t)BATCH * NG * 2);// 4.2 MB
    unsigned short* hpp     = (unsigned short*)alloc(2 * SLAB * 2);          // 2 MB
    float*          cst     = (float*)alloc(SLAB * 4);                       // 2 MB
    float*          Wcomb_f = (float*)alloc((size_t)NG * HN * 4);            // 1 MB
    unsigned short* Wf_enc  = (unsigned short*)alloc((size_t)NG * HN * 2);
    unsigned short* Wf_dec0 = (unsigned short*)alloc((size_t)NG * HN * 2);
    unsigned short* Wf_dec  = (unsigned short*)alloc((size_t)NG * HN * 2);
    unsigned short* oWf     = (unsigned short*)alloc((size_t)NOF * 8 * 64 * 8 * 2);
    unsigned short* L0b     = (unsigned short*)alloc((size_t)BATCH * KP * 2);
    unsigned short* Wihe_p  = (unsigned short*)alloc((size_t)NG * KP * 2);
    unsigned short* Wdihl_p = (unsigned short*)alloc((size_t)NG * KP * 2);
    unsigned short* oWp     = (unsigned short*)alloc((size_t)KP * HN * 2);
    float*          Wc_p    = (float*)alloc((size_t)NG * 2 * 4);
    float*          ebp     = (float*)alloc(NG * 4);
    float*          dbp     = (float*)alloc(NG * 4);
    float*          biasf   = (float*)alloc(NG * 4);

    pack_w<<<(BATCH * KP + 255) / 256, 256, 0, stream>>>(
        past, eWih, eb, dWih, db, oW,
        L0b, Wihe_p, Wdihl_p, oWp, Wc_p, ebp, dbp);
    wcomb_kernel<<<NG / 4, 256, 0, stream>>>(dWih, dWhh, oW, Wcomb_f);
    biasf_kernel<<<(NG + 255) / 256, 256, 0, stream>>>(dWih, db, ob, biasf);
    pack_wfrag<<<(3 * NG * HN + 255) / 256, 256, 0, stream>>>(
        eWhh, dWhh, Wcomb_f, Wf_enc, Wf_dec0, Wf_dec);
    pack_owf<<<(NOF * 8 * 64 * 8 + 255) / 256, 256, 0, stream>>>(oW, oWf);
    init_hc<<<(BATCH * HN + 255) / 256, 256, 0, stream>>>(hpp, cst);
    pack_xb<<<(MR * (KP / 8) + 255) / 256, 256, 0, stream>>>(past, Xb);

    // xw = Xb @ Wihe^T + eb  (bf16 out, t-major rows)
    gemm_fast<2><<<dim3(NG / 128, MR / 128), 256, 0, stream>>>(
        Xb, Wihe_p, ebp, xw, KP, NG);
    // l0wb = lidar0 @ Wl^T + db (bf16 slab, same layout as xw slabs)
    gemm_fast<2><<<dim3(NG / 128, BATCH / 128), 256, 0, stream>>>(
        L0b, Wdihl_p, dbp, l0wb, KP, NG);

    // ---- encoder: 50 relaunched steps, h ping-pong in hpp ----
    for (int t = 0; t < TN; ++t) {
        const unsigned short* hs = hpp + (size_t)(t & 1) * SLAB;
        unsigned short*       hd = hpp + (size_t)((t + 1) & 1) * SLAB;
        step3<0><<<256, 512, 0, stream>>>(
            hs, Wf_enc, xw + (size_t)t * BATCH * NG,
            nullptr, nullptr, nullptr, nullptr, nullptr, nullptr, 0, cst, hd);
    }
    // ---- decoder step 0 (additive = l0wb + cmd), h -> hdec[0] ----
    step3<1><<<256, 512, 0, stream>>>(
        hpp + (size_t)(TN & 1) * SLAB, Wf_dec0, l0wb,
        nullptr, Wc_p, cmds, nullptr, nullptr, nullptr, 0, cst, hdec);
    // ---- decoder steps 1..49 (folded recurrence + fused outproj of h_{t-1}) ----
    for (int t = 1; t < TN; ++t) {
        step3<2><<<256, 512, 0, stream>>>(
            hdec + (size_t)(t - 1) * SLAB, Wf_dec, nullptr,
            biasf, Wc_p, cmds + (size_t)t * CMDN,
            oWf, ob, out, t - 1, cst, hdec + (size_t)t * SLAB);
    }
    // ---- tail: out[:, 49, :] = hdec[49] @ oW^T + ob ----
    gemm_fast<3><<<dim3(KP / 128, BATCH / 128), 256, 0, stream>>>(
        hdec + (size_t)(TN - 1) * SLAB, oWp, ob, out, HN, 0);
}

// Round 11
// 1124.700 us; speedup vs baseline: 3.8425x; 1.2165x over previous
//
#include <hip/hip_runtime.h>
#include <hip/hip_bf16.h>
#include <math.h>

#define CMDN   2
#define LIDARN 360
#define HN     256
#define TN     50
#define BATCH  2048
#define KXN    362              // CMD+LIDAR
#define NG     1024             // 4*H gate columns
#define KP     384              // padded x-K for big GEMMs
#define MR     (TN*BATCH)       // 102400 rows (t-major: r = t*2048 + b)
#define SLAB   ((size_t)BATCH*HN)
#define NOF    24               // out col fragments (24*16 = 384 >= 360)

typedef __attribute__((ext_vector_type(8))) short bf16x8;
typedef __attribute__((ext_vector_type(4))) float f32x4;

__device__ inline unsigned short f2b(float f) {
    unsigned int x = __builtin_bit_cast(unsigned int, f);
    x += 0x7FFFu + ((x >> 16) & 1u);
    return (unsigned short)(x >> 16);
}
__device__ inline float b2f(unsigned short u) {
    unsigned int x = ((unsigned int)u) << 16;
    return __builtin_bit_cast(float, x);
}
__device__ inline float sigf(float x)  { return 1.f / (1.f + __expf(-x)); }
__device__ inline float tanhfa(float x){ return 2.f / (1.f + __expf(-2.f * x)) - 1.f; }

// packed gate-col order: p = 4*u + g  ->  original row jorig = g*256 + u
__device__ inline int p2j(int p) { return ((p & 3) << 8) + (p >> 2); }

typedef const __attribute__((address_space(1))) unsigned int* gp1_t;
typedef __attribute__((address_space(3))) unsigned int* lp3_t;
__device__ inline void gload16(const void* g, void* l) {
    __builtin_amdgcn_global_load_lds((gp1_t)g, (lp3_t)l, 16, 0, 0);
}

// ---------------------------------------------------------------------------
// Pack past fp32 -> Xb bf16 [MR][KP] t-major (r = t*2048 + b), zero-padded.
// ---------------------------------------------------------------------------
__global__ __launch_bounds__(256) void pack_xb(
    const float* __restrict__ past, unsigned short* __restrict__ Xb)
{
    int c = blockIdx.x * 256 + threadIdx.x;      // chunk of 8 elems
    if (c >= MR * (KP / 8)) return;
    int r = c / (KP / 8), kc = c - r * (KP / 8);
    int b = r & 2047, t = r >> 11;
    const float* p = past + ((size_t)b * TN + t) * KXN;
    const int k = kc * 8;
    bf16x8 v;
    if (k + 8 <= KXN) {
        float2 f0 = *(const float2*)(p + k);
        float2 f1 = *(const float2*)(p + k + 2);
        float2 f2 = *(const float2*)(p + k + 4);
        float2 f3 = *(const float2*)(p + k + 6);
        v[0] = (short)f2b(f0.x); v[1] = (short)f2b(f0.y);
        v[2] = (short)f2b(f1.x); v[3] = (short)f2b(f1.y);
        v[4] = (short)f2b(f2.x); v[5] = (short)f2b(f2.y);
        v[6] = (short)f2b(f3.x); v[7] = (short)f2b(f3.y);
    } else {
        #pragma unroll
        for (int e = 0; e < 8; ++e)
            v[e] = (k + e < KXN) ? (short)f2b(p[k + e]) : (short)0;
    }
    *(bf16x8*)&Xb[(size_t)r * KP + k] = v;
}

// ---------------------------------------------------------------------------
// 128x128 MFMA GEMM, global_load_lds(16B) staging, XOR-swizzled source +
// swizzled ds_read (linear LDS dest). Chunked XCD swizzle (nwg % 8 == 0).
// OMODE 0: C f32 = acc+bias. OMODE 2: C bf16 = acc+bias.
// OMODE 3: tail outproj: out[row][TN-1][col] = acc+ob[col], col<360.
// ---------------------------------------------------------------------------
template<int OMODE>
__global__ __launch_bounds__(256) void gemm_fast(
    const unsigned short* __restrict__ A,
    const unsigned short* __restrict__ B,
    const float* __restrict__ bias,
    void* __restrict__ Cv, int K, int ldc)
{
    __shared__ __align__(16) unsigned short As[128 * 32];
    __shared__ __align__(16) unsigned short Bs[128 * 32];

    const int nwg = gridDim.x * gridDim.y;
    const int hid = blockIdx.y * gridDim.x + blockIdx.x;
    const int lid = (hid & 7) * (nwg >> 3) + (hid >> 3);
    const int bx  = lid % gridDim.x;
    const int by  = lid / gridDim.x;

    const int tid  = threadIdx.x;
    const int lane = tid & 63;
    const int wv   = tid >> 6;
    const int wm   = wv >> 1, wn = wv & 1;
    const int r0   = by * 128;
    const int n0   = bx * 128;
    const int l15  = lane & 15;
    const int lhi  = lane >> 4;

    const int srow = lane >> 2;          // 0..15 within chunk
    const int sc   = lane & 3;           // 16B chunk within 64B row

    f32x4 acc[4][4] = {};

    for (int k0 = 0; k0 < K; k0 += 32) {
        #pragma unroll
        for (int j = 0; j < 2; ++j) {
            const int rl = (wv * 2 + j) * 16 + srow;        // LDS row 0..127
            const int cs = sc ^ (rl & 3);                    // swizzled src chunk
            gload16(&A[(size_t)(r0 + rl) * K + k0 + cs * 8], &As[(wv * 2 + j) * 512]);
            gload16(&B[(size_t)(n0 + rl) * K + k0 + cs * 8], &Bs[(wv * 2 + j) * 512]);
        }
        __syncthreads();
        bf16x8 a[4], b[4];
        #pragma unroll
        for (int i = 0; i < 4; ++i) {
            const int ra = wm * 64 + i * 16 + l15;
            const int rb = wn * 64 + i * 16 + l15;
            a[i] = *(const bf16x8*)&As[ra * 32 + (lhi ^ (ra & 3)) * 8];
            b[i] = *(const bf16x8*)&Bs[rb * 32 + (lhi ^ (rb & 3)) * 8];
        }
        #pragma unroll
        for (int mi = 0; mi < 4; ++mi)
            #pragma unroll
            for (int ni = 0; ni < 4; ++ni)
                acc[mi][ni] = __builtin_amdgcn_mfma_f32_16x16x32_bf16(a[mi], b[ni], acc[mi][ni], 0, 0, 0);
        __syncthreads();
    }

    #pragma unroll
    for (int mi = 0; mi < 4; ++mi) {
        const int rowb = r0 + wm * 64 + mi * 16 + ((lane >> 4) << 2);
        #pragma unroll
        for (int ni = 0; ni < 4; ++ni) {
            const int col = n0 + wn * 64 + ni * 16 + l15;
            #pragma unroll
            for (int r = 0; r < 4; ++r) {
                const int row = rowb + r;
                float v = acc[mi][ni][r];
                if (OMODE == 0) {
                    ((float*)Cv)[(size_t)row * ldc + col] = v + bias[col];
                } else if (OMODE == 2) {
                    ((unsigned short*)Cv)[(size_t)row * ldc + col] = f2b(v + bias[col]);
                } else {
                    if (col < LIDARN)
                        ((float*)Cv)[(size_t)row * (TN * LIDARN) + (size_t)(TN - 1) * LIDARN + col]
                            = v + bias[col];
                }
            }
        }
    }
}

// ---------------------------------------------------------------------------
// Recurrent step v4: 512 blocks x 512 threads (2 blocks/CU -> 4 waves/SIMD).
// bid = cg*64 + rg (bid%8 = rg%8: cg-peers of a rg share an XCD heuristic).
// Block: 32 batch rows x 128 gate cols; wave owns 16 cols x 32 rows (2 mf).
// h staged to LDS (padded 264); W direct from L2 (frag-packed); additive slab
// in LDS; c in TRANSPOSED global f32 ct[u][row] -> float4 per lane.
// MODE 2 fuses outproj of staged h (= h_{t-1}) -> out[:, tprev, :] slice.
// ---------------------------------------------------------------------------
template<int MODE>
__global__ __launch_bounds__(512, 4) void step4(
    const unsigned short* __restrict__ hsrc,   // [2048][256] bf16
    const unsigned short* __restrict__ Wf,     // frag-packed [64cf][8kf][64][8]
    const unsigned short* __restrict__ addb,   // MODE<=1: slab [2048][1024] bf16
    const float* __restrict__ biasf,           // MODE 2
    const float* __restrict__ cmdw,            // [1024][2]  (MODE>=1)
    const float* __restrict__ cmds_t,          // cmds + t*2 (MODE>=1), row stride 100
    const unsigned short* __restrict__ oWf,    // MODE 2: frag-packed [24f][8kf][64][8]
    const float* __restrict__ ob,              // MODE 2
    float* __restrict__ out,                   // MODE 2: [2048][50][360] f32
    int tprev,                                 // MODE 2: time index for out
    float* __restrict__ ct,                    // [256u][2048row] f32 (transposed)
    unsigned short* __restrict__ hdst)         // [2048][256] bf16
{
    __shared__ __align__(16) unsigned short Hl[32 * 264];   // 16.5 KB
    __shared__ __align__(16) unsigned short Xl[32 * 128];   // 8 KB
    __shared__ float cmdl[32][2];

    const int tid  = threadIdx.x;
    const int lane = tid & 63;
    const int w    = tid >> 6;            // wave 0..7
    const int l15  = lane & 15;
    const int lhi  = lane >> 4;
    const int g    = l15 & 3;             // 0=i 1=f 2=g 3=o
    const int cg   = blockIdx.x >> 6;     // 0..7
    const int rg   = blockIdx.x & 63;     // 0..63
    const int r0   = rg * 32;

    // ---- stage h (coalesced 16B): 32 rows x 256 cols ----
    #pragma unroll
    for (int i = 0; i < 2; ++i) {
        const int c = i * 512 + tid;          // 0..1023
        const int row = c >> 5, col8 = c & 31;
        *(bf16x8*)&Hl[row * 264 + col8 * 8] =
            *(const bf16x8*)&hsrc[(size_t)(r0 + row) * HN + col8 * 8];
    }
    // ---- stage additive slab: 32 rows x 128 cols ----
    if (MODE <= 1) {
        const unsigned short* xs = addb + (size_t)r0 * NG + cg * 128;
        const int row = tid >> 4, col8 = tid & 15;
        *(bf16x8*)&Xl[row * 128 + col8 * 8] =
            *(const bf16x8*)&xs[(size_t)row * NG + col8 * 8];
    }
    if (MODE >= 1 && tid < 32) {
        const float2 cv = *(const float2*)&cmds_t[(size_t)(r0 + tid) * (TN * CMDN)];
        cmdl[tid][0] = cv.x; cmdl[tid][1] = cv.y;
    }
    __syncthreads();

    // ---- gates K loop: A from LDS, B direct from L2 (frag-packed) ----
    const unsigned short* wb = Wf + (size_t)(cg * 8 + w) * 4096;
    f32x4 acc[2] = {};
    #pragma unroll
    for (int kf = 0; kf < 8; ++kf) {
        bf16x8 b = *(const bf16x8*)&wb[(size_t)(kf * 64 + lane) * 8];
        #pragma unroll
        for (int mf = 0; mf < 2; ++mf) {
            bf16x8 a = *(const bf16x8*)&Hl[(mf * 16 + l15) * 264 + kf * 32 + lhi * 8];
            acc[mf] = __builtin_amdgcn_mfma_f32_16x16x32_bf16(a, b, acc[mf], 0, 0, 0);
        }
    }

    // ---- fused outproj of staged h (MODE 2): wave w -> strip s=w&1,
    //      frag f=w>>1 (waves with f==3 idle) ----
    f32x4 acc_o = {};
    const int s_o = w & 1;
    const int f_o = w >> 1;
    if (MODE == 2 && f_o < 3) {
        const int fg = cg * 3 + f_o;
        #pragma unroll
        for (int kf = 0; kf < 8; ++kf) {
            bf16x8 a = *(const bf16x8*)&Hl[(s_o * 16 + l15) * 264 + kf * 32 + lhi * 8];
            bf16x8 b = *(const bf16x8*)&oWf[(size_t)((fg * 8 + kf) * 64 + lane) * 8];
            acc_o = __builtin_amdgcn_mfma_f32_16x16x32_bf16(a, b, acc_o, 0, 0, 0);
        }
    }

    // ---- fused cell epilogue (c as float4 in transposed layout) ----
    const int p = cg * 128 + w * 16 + l15;
    const int u = cg * 32 + w * 4 + (l15 >> 2);
    float w0_r = 0.f, w1_r = 0.f, bf_r = 0.f;
    if (MODE >= 1) { w0_r = cmdw[p * 2]; w1_r = cmdw[p * 2 + 1]; }
    if (MODE == 2) bf_r = biasf[p];
    #pragma unroll
    for (int mf = 0; mf < 2; ++mf) {
        float* cp = (g == 0) ? &ct[(size_t)u * BATCH + r0 + mf * 16 + lhi * 4] : nullptr;
        f32x4 c4 = (g == 0) ? *(const f32x4*)cp : f32x4{0.f, 0.f, 0.f, 0.f};
        #pragma unroll
        for (int r = 0; r < 4; ++r) {
            const int rw = mf * 16 + lhi * 4 + r;
            float v = acc[mf][r];
            if (MODE <= 1) v += b2f(Xl[rw * 128 + w * 16 + l15]);
            if (MODE == 2) v += bf_r;
            if (MODE >= 1) v += cmdl[rw][0] * w0_r + cmdl[rw][1] * w1_r;
            float act = (g == 2) ? tanhfa(v) : sigf(v);
            float a1 = __shfl_xor(act, 1);
            float a2 = __shfl_xor(act, 2);
            float a3 = __shfl_xor(act, 3);
            if (g == 0) {                      // lane holds i; a1=f a2=g a3=o
                float cc = a1 * c4[r] + act * a2;
                c4[r] = cc;
                hdst[(size_t)(r0 + rw) * HN + u] = f2b(a3 * tanhfa(cc));
            }
        }
        if (g == 0) *(f32x4*)cp = c4;
    }

    // ---- out slice store (MODE 2) ----
    if (MODE == 2 && f_o < 3) {
        const int col = (cg * 3 + f_o) * 16 + l15;
        if (col < LIDARN) {
            const float bo = ob[col];
            #pragma unroll
            for (int r = 0; r < 4; ++r) {
                const int brow = r0 + s_o * 16 + lhi * 4 + r;
                out[(size_t)brow * (TN * LIDARN) + (size_t)tprev * LIDARN + col]
                    = acc_o[r] + bo;
            }
        }
    }
}

// ---------------------------------------------------------------------------
// Packs / folds (one-time)
// ---------------------------------------------------------------------------
__global__ __launch_bounds__(256) void pack_w(
    const float* __restrict__ past,
    const float* __restrict__ eWih, const float* __restrict__ eb,
    const float* __restrict__ dWih, const float* __restrict__ db,
    const float* __restrict__ oW,
    unsigned short* __restrict__ L0b,      // [2048][384]
    unsigned short* __restrict__ Wihe_p,   // [1024][384] p-order
    unsigned short* __restrict__ Wdihl_p,  // [1024][384] p-order
    unsigned short* __restrict__ oWp,      // [384][256]
    float* __restrict__ Wc_p,              // [1024][2]
    float* __restrict__ ebp, float* __restrict__ dbp)
{
    int idx = blockIdx.x * 256 + threadIdx.x;
    if (idx < BATCH * KP) {                // L0b: lidar0 = past[:, -1, 2:]
        int b = idx / KP, k = idx - b * KP;
        L0b[idx] = (k < LIDARN)
            ? f2b(past[((size_t)b * TN + (TN - 1)) * KXN + CMDN + k]) : (unsigned short)0;
    }
    if (idx < NG * KP) {
        int p = idx / KP, k = idx - p * KP;
        int j = p2j(p);
        Wihe_p[idx]  = (k < KXN)    ? f2b(eWih[(size_t)j * KXN + k]) : (unsigned short)0;
        Wdihl_p[idx] = (k < LIDARN) ? f2b(dWih[(size_t)j * KXN + k]) : (unsigned short)0;
        if (k < 2) Wc_p[p * 2 + k] = dWih[(size_t)j * KXN + LIDARN + k];
        if (k == 0) { ebp[p] = eb[j]; dbp[p] = db[j]; }
    }
    if (idx < KP * HN) {
        int n = idx / HN, k = idx - n * HN;
        oWp[idx] = (n < LIDARN) ? f2b(oW[(size_t)n * HN + k]) : (unsigned short)0;
    }
}

// Wcomb_f[p][k] = dWhh[j][k] + sum_n dWih[j][n] * oW[n][k]; 4 p per block.
__global__ __launch_bounds__(256) void wcomb_kernel(
    const float* __restrict__ dWih, const float* __restrict__ dWhh,
    const float* __restrict__ oW, float* __restrict__ Wcomb_f)
{
    const int pb = blockIdx.x * 4, k = threadIdx.x;
    int j0 = p2j(pb), j1 = p2j(pb + 1), j2 = p2j(pb + 2), j3 = p2j(pb + 3);
    float s0 = dWhh[(size_t)j0 * HN + k];
    float s1 = dWhh[(size_t)j1 * HN + k];
    float s2 = dWhh[(size_t)j2 * HN + k];
    float s3 = dWhh[(size_t)j3 * HN + k];
    #pragma unroll 4
    for (int n = 0; n < LIDARN; ++n) {
        const float ow = oW[(size_t)n * HN + k];
        s0 += dWih[(size_t)j0 * KXN + n] * ow;
        s1 += dWih[(size_t)j1 * KXN + n] * ow;
        s2 += dWih[(size_t)j2 * KXN + n] * ow;
        s3 += dWih[(size_t)j3 * KXN + n] * ow;
    }
    Wcomb_f[(size_t)pb * HN + k]            = s0;
    Wcomb_f[(size_t)(pb + 1) * HN + k]      = s1;
    Wcomb_f[(size_t)(pb + 2) * HN + k]      = s2;
    Wcomb_f[(size_t)(pb + 3) * HN + k]      = s3;
}

// biasf[p] = db[j] + sum_n dWih[j][n] * ob[n]
__global__ __launch_bounds__(256) void biasf_kernel(
    const float* __restrict__ dWih, const float* __restrict__ db,
    const float* __restrict__ ob, float* __restrict__ biasf)
{
    int p = blockIdx.x * 256 + threadIdx.x;
    if (p >= NG) return;
    int j = p2j(p);
    float s = db[j];
    for (int n = 0; n < LIDARN; ++n)
        s += dWih[(size_t)j * KXN + n] * ob[n];
    biasf[p] = s;
}

// Fragment-pack three recurrence weights.
__global__ __launch_bounds__(256) void pack_wfrag(
    const float* __restrict__ eWhh, const float* __restrict__ dWhh,
    const float* __restrict__ Wcomb_f,
    unsigned short* __restrict__ Wf_enc,
    unsigned short* __restrict__ Wf_dec0,
    unsigned short* __restrict__ Wf_dec)
{
    const int NW = NG * HN;                      // 262144
    int idx = blockIdx.x * 256 + threadIdx.x;
    if (idx >= 3 * NW) return;
    int sel = idx / NW;
    int d   = idx - sel * NW;
    int e    = d & 7;
    int lane = (d >> 3) & 63;
    int kf   = (d >> 9) & 7;
    int cf   = d >> 12;
    int p = cf * 16 + (lane & 15);
    int k = kf * 32 + (lane >> 4) * 8 + e;
    if (sel == 0)      Wf_enc[d]  = f2b(eWhh[(size_t)p2j(p) * HN + k]);
    else if (sel == 1) Wf_dec0[d] = f2b(dWhh[(size_t)p2j(p) * HN + k]);
    else               Wf_dec[d]  = f2b(Wcomb_f[(size_t)p * HN + k]);
}

// Fragment-pack outproj weights: 24 col-frags, rows >= 360 zero.
__global__ __launch_bounds__(256) void pack_owf(
    const float* __restrict__ oW, unsigned short* __restrict__ oWf)
{
    int d = blockIdx.x * 256 + threadIdx.x;
    if (d >= NOF * 8 * 64 * 8) return;           // 98304
    int e = d & 7, lane = (d >> 3) & 63, kf = (d >> 9) & 7, f = d >> 12;
    int n = f * 16 + (lane & 15);
    int k = kf * 32 + (lane >> 4) * 8 + e;
    oWf[d] = (n < LIDARN) ? f2b(oW[(size_t)n * HN + k]) : (unsigned short)0;
}

// h0 = 0 (bf16), ct = 0 (f32, transposed [256][2048])
__global__ __launch_bounds__(256) void init_hc(
    unsigned short* __restrict__ h0, float* __restrict__ ct)
{
    int idx = blockIdx.x * 256 + threadIdx.x;
    if (idx < BATCH * HN) { h0[idx] = 0; ct[idx] = 0.f; }
}

extern "C" void kernel_launch(void* const* d_in, const int* in_sizes, int n_in,
                              void* d_out, int out_size, void* d_ws, size_t ws_size,
                              hipStream_t stream)
{
    const float* past = (const float*)d_in[0];
    const float* cmds = (const float*)d_in[1];
    const float* eWih = (const float*)d_in[2];
    const float* eWhh = (const float*)d_in[3];
    const float* eb   = (const float*)d_in[4];
    const float* dWih = (const float*)d_in[5];
    const float* dWhh = (const float*)d_in[6];
    const float* db   = (const float*)d_in[7];
    const float* oW   = (const float*)d_in[8];
    const float* ob   = (const float*)d_in[9];
    float* out = (float*)d_out;

    char* w = (char*)d_ws;
    auto alloc = [&](size_t bytes) {
        char* p = w; w += (bytes + 255) & ~(size_t)255; return p;
    };
    unsigned short* xw      = (unsigned short*)alloc((size_t)MR * NG * 2);   // 209.7 MB
    unsigned short* Xb      = (unsigned short*)alloc((size_t)MR * KP * 2);   // 78.6 MB
    unsigned short* hdec    = (unsigned short*)alloc((size_t)MR * HN * 2);   // 52.4 MB
    unsigned short* l0wb    = (unsigned short*)alloc((size_t)BATCH * NG * 2);// 4.2 MB
    unsigned short* hpp     = (unsigned short*)alloc(2 * SLAB * 2);          // 2 MB
    float*          ct      = (float*)alloc(SLAB * 4);                       // 2 MB
    float*          Wcomb_f = (float*)alloc((size_t)NG * HN * 4);            // 1 MB
    unsigned short* Wf_enc  = (unsigned short*)alloc((size_t)NG * HN * 2);
    unsigned short* Wf_dec0 = (unsigned short*)alloc((size_t)NG * HN * 2);
    unsigned short* Wf_dec  = (unsigned short*)alloc((size_t)NG * HN * 2);
    unsigned short* oWf     = (unsigned short*)alloc((size_t)NOF * 8 * 64 * 8 * 2);
    unsigned short* L0b     = (unsigned short*)alloc((size_t)BATCH * KP * 2);
    unsigned short* Wihe_p  = (unsigned short*)alloc((size_t)NG * KP * 2);
    unsigned short* Wdihl_p = (unsigned short*)alloc((size_t)NG * KP * 2);
    unsigned short* oWp     = (unsigned short*)alloc((size_t)KP * HN * 2);
    float*          Wc_p    = (float*)alloc((size_t)NG * 2 * 4);
    float*          ebp     = (float*)alloc(NG * 4);
    float*          dbp     = (float*)alloc(NG * 4);
    float*          biasf   = (float*)alloc(NG * 4);

    pack_w<<<(BATCH * KP + 255) / 256, 256, 0, stream>>>(
        past, eWih, eb, dWih, db, oW,
        L0b, Wihe_p, Wdihl_p, oWp, Wc_p, ebp, dbp);
    wcomb_kernel<<<NG / 4, 256, 0, stream>>>(dWih, dWhh, oW, Wcomb_f);
    biasf_kernel<<<(NG + 255) / 256, 256, 0, stream>>>(dWih, db, ob, biasf);
    pack_wfrag<<<(3 * NG * HN + 255) / 256, 256, 0, stream>>>(
        eWhh, dWhh, Wcomb_f, Wf_enc, Wf_dec0, Wf_dec);
    pack_owf<<<(NOF * 8 * 64 * 8 + 255) / 256, 256, 0, stream>>>(oW, oWf);
    init_hc<<<(BATCH * HN + 255) / 256, 256, 0, stream>>>(hpp, ct);
    pack_xb<<<(MR * (KP / 8) + 255) / 256, 256, 0, stream>>>(past, Xb);

    // xw = Xb @ Wihe^T + eb  (bf16 out, t-major rows)
    gemm_fast<2><<<dim3(NG / 128, MR / 128), 256, 0, stream>>>(
        Xb, Wihe_p, ebp, xw, KP, NG);
    // l0wb = lidar0 @ Wl^T + db (bf16 slab, same layout as xw slabs)
    gemm_fast<2><<<dim3(NG / 128, BATCH / 128), 256, 0, stream>>>(
        L0b, Wdihl_p, dbp, l0wb, KP, NG);

    // ---- encoder: 50 relaunched steps, h ping-pong in hpp ----
    for (int t = 0; t < TN; ++t) {
        const unsigned short* hs = hpp + (size_t)(t & 1) * SLAB;
        unsigned short*       hd = hpp + (size_t)((t + 1) & 1) * SLAB;
        step4<0><<<512, 512, 0, stream>>>(
            hs, Wf_enc, xw + (size_t)t * BATCH * NG,
            nullptr, nullptr, nullptr, nullptr, nullptr, nullptr, 0, ct, hd);
    }
    // ---- decoder step 0 (additive = l0wb + cmd), h -> hdec[0] ----
    step4<1><<<512, 512, 0, stream>>>(
        hpp + (size_t)(TN & 1) * SLAB, Wf_dec0, l0wb,
        nullptr, Wc_p, cmds, nullptr, nullptr, nullptr, 0, ct, hdec);
    // ---- decoder steps 1..49 (folded recurrence + fused outproj of h_{t-1}) ----
    for (int t = 1; t < TN; ++t) {
        step4<2><<<512, 512, 0, stream>>>(
            hdec + (size_t)(t - 1) * SLAB, Wf_dec, nullptr,
            biasf, Wc_p, cmds + (size_t)t * CMDN,
            oWf, ob, out, t - 1, ct, hdec + (size_t)t * SLAB);
    }
    // ---- tail: out[:, 49, :] = hdec[49] @ oW^T + ob ----
    gemm_fast<3><<<dim3(KP / 128, BATCH / 128), 256, 0, stream>>>(
        hdec + (size_t)(TN - 1) * SLAB, oWp, ob, out, HN, 0);
}